// Round 9
// baseline (423.627 us; speedup 1.0000x reference)
//
#include <hip/hip_runtime.h>

#define B_ 2
#define L_ 2048
#define D_ 768
#define H_ 8
#define DK_ 64
#define DV_ 96
#define NPOS_ 32

typedef __attribute__((ext_vector_type(8))) __bf16 bf16x8;
typedef __attribute__((ext_vector_type(4))) float f32x4;

static __device__ __forceinline__ float bs2f(short s) {
    return (float)__builtin_bit_cast(__bf16, s);
}
static __device__ __forceinline__ short f2bs(float f) {
    return __builtin_bit_cast(short, (__bf16)f);
}

// ---------------------------------------------------------------------------
// prep: blocks 0..1055 transpose+convert all weights (wq/wk/wv packed into
// wqkvT[1792][768]); block 1056 builds sidx table + adjusted VU/VS tables:
// VU = 0.125*(suffix(v.wpos) - suffix(u.wpos))   [u-part corrects the q+u fold]
// sidx[d+2047]: s<17 -> d>0 (SU+SS), 17..33 -> d<0 (SU-SS), 34 -> d==0 (SU).
// ---------------------------------------------------------------------------
__global__ __launch_bounds__(256) void prep_kernel(
    const float* __restrict__ wq, const float* __restrict__ wk,
    const float* __restrict__ wv, const float* __restrict__ wo,
    const float* __restrict__ w1, const float* __restrict__ w2,
    const float* __restrict__ vparam, const float* __restrict__ uparam,
    const float* __restrict__ wpos,
    short* __restrict__ wqkvT, short* __restrict__ woT,
    short* __restrict__ w1T, short* __restrict__ w2T,
    unsigned char* __restrict__ sidx, float* __restrict__ VU, float* __restrict__ VS)
{
    __shared__ short T[64][66];
    __shared__ float vw[H_ * NPOS_];
    __shared__ float uw[H_ * NPOS_];
    int blk = blockIdx.x, tid = threadIdx.x;
    if (blk < 1056) {
        const float* W; short* Wt; int K, N, bx, by;
        if (blk < 96)       { W = wq; Wt = wqkvT;              K = 768;  N = 512;  int b = blk;       bx = b % 8;  by = b / 8; }
        else if (blk < 192) { W = wk; Wt = wqkvT + 512 * 768;  K = 768;  N = 512;  int b = blk - 96;  bx = b % 8;  by = b / 8; }
        else if (blk < 336) { W = wv; Wt = wqkvT + 1024 * 768; K = 768;  N = 768;  int b = blk - 192; bx = b % 12; by = b / 12; }
        else if (blk < 480) { W = wo; Wt = woT;                K = 768;  N = 768;  int b = blk - 336; bx = b % 12; by = b / 12; }
        else if (blk < 768) { W = w1; Wt = w1T;                K = 768;  N = 1536; int b = blk - 480; bx = b % 24; by = b / 24; }
        else                { W = w2; Wt = w2T;                K = 1536; N = 768;  int b = blk - 768; bx = b % 12; by = b / 12; }
        int n0 = bx << 6, k0 = by << 6;
        for (int idx = tid; idx < 4096; idx += 256) {
            int r = idx >> 6, c = idx & 63;
            T[c][r] = f2bs(W[(size_t)(k0 + r) * N + n0 + c]);
        }
        __syncthreads();
        for (int idx = tid; idx < 4096; idx += 256) {
            int r = idx >> 6, c = idx & 63;
            Wt[(size_t)(n0 + r) * K + k0 + c] = T[r][c];
        }
    } else {
        float pr = expf(logf((L_ + 1) / 2.0f) / (NPOS_ / 2));
        for (int idx = tid; idx < 4095; idx += 256) {
            int d = idx - 2047;
            int ad = d < 0 ? -d : d;
            int c = 0;
            for (int m = 1; m <= NPOS_ / 2; ++m) {
                float cw = powf(pr, (float)m);
                if (cw < (float)ad) c++;
            }
            sidx[idx] = (unsigned char)(d > 0 ? c : (d < 0 ? 17 + c : 34));
        }
        {
            int h = tid >> 5, n = tid & 31;
            float av = 0.f, au = 0.f;
            for (int d = 0; d < DK_; ++d) {
                float wp = wpos[(h * DK_ + d) * NPOS_ + n];
                av += vparam[h * DK_ + d] * wp;
                au += uparam[h * DK_ + d] * wp;
            }
            vw[tid] = av;
            uw[tid] = au;
        }
        __syncthreads();
        if (tid < H_ * 17) {
            int h = tid / 17, m = tid % 17;
            float su = 0.f, ss = 0.f;
            for (int t2 = m; t2 < 16; ++t2) {
                su += vw[h * NPOS_ + t2] - uw[h * NPOS_ + t2];
                ss += vw[h * NPOS_ + 16 + t2] - uw[h * NPOS_ + 16 + t2];
            }
            VU[h * 17 + m] = su * 0.125f;
            VS[h * 17 + m] = ss * 0.125f;
        }
    }
}

// ---------------------------------------------------------------------------
// RMSNorm (row of 768), fp32 in, bf16 out
// ---------------------------------------------------------------------------
__global__ __launch_bounds__(256) void rmsnorm_kernel(
    const float* __restrict__ x, const float* __restrict__ wgt, short* __restrict__ out)
{
    int row = blockIdx.x, tid = threadIdx.x;
    __shared__ float red[4];
    const float* xr = x + (size_t)row * D_;
    float ss = 0.f;
    for (int c = tid; c < D_; c += 256) { float f = xr[c]; ss += f * f; }
    for (int msk = 1; msk < 64; msk <<= 1) ss += __shfl_xor(ss, msk);
    if ((tid & 63) == 0) red[tid >> 6] = ss;
    __syncthreads();
    float tot = red[0] + red[1] + red[2] + red[3];
    float sc = rsqrtf(tot * (1.f / D_) + 1e-5f);
    for (int c = tid; c < D_; c += 256)
        out[(size_t)row * D_ + c] = f2bs(xr[c] * sc * wgt[c]);
}

// ---------------------------------------------------------------------------
// 64x64-tile bf16 MFMA GEMM (N=768 shapes: wo, FFN2)
// ---------------------------------------------------------------------------
__global__ __launch_bounds__(256) void gemm64(
    const short* __restrict__ A, const short* __restrict__ Bt,
    const float* __restrict__ bias, const float* __restrict__ resid,
    void* __restrict__ outp,
    int M, int N, int K, int act, int out_f32)
{
    __shared__ __align__(16) short Al[64 * 72];
    __shared__ __align__(16) short Bl[64 * 72];
    int tid = threadIdx.x;
    int w = tid >> 6, lane = tid & 63, quad = lane >> 4, t = lane & 15;
    int m0b = blockIdx.y << 6, n0b = blockIdx.x << 6;
    int wr = (w >> 1) << 5, wc = (w & 1) << 5;
    f32x4 acc[2][2] = {};
    for (int kb = 0; kb < K; kb += 64) {
        __syncthreads();
#pragma unroll
        for (int it = 0; it < 2; ++it) {
            int idx = tid + (it << 8);
            int r = idx >> 3, c8 = (idx & 7) << 3;
            *(bf16x8*)&Al[r * 72 + c8] = *(const bf16x8*)&A[(size_t)(m0b + r) * K + kb + c8];
            *(bf16x8*)&Bl[r * 72 + c8] = *(const bf16x8*)&Bt[(size_t)(n0b + r) * K + kb + c8];
        }
        __syncthreads();
#pragma unroll
        for (int ks = 0; ks < 2; ++ks) {
            bf16x8 af0 = *(bf16x8*)&Al[(wr + t) * 72 + (ks << 5) + (quad << 3)];
            bf16x8 af1 = *(bf16x8*)&Al[(wr + 16 + t) * 72 + (ks << 5) + (quad << 3)];
            bf16x8 bf0 = *(bf16x8*)&Bl[(wc + t) * 72 + (ks << 5) + (quad << 3)];
            bf16x8 bf1 = *(bf16x8*)&Bl[(wc + 16 + t) * 72 + (ks << 5) + (quad << 3)];
            acc[0][0] = __builtin_amdgcn_mfma_f32_16x16x32_bf16(af0, bf0, acc[0][0], 0, 0, 0);
            acc[0][1] = __builtin_amdgcn_mfma_f32_16x16x32_bf16(af0, bf1, acc[0][1], 0, 0, 0);
            acc[1][0] = __builtin_amdgcn_mfma_f32_16x16x32_bf16(af1, bf0, acc[1][0], 0, 0, 0);
            acc[1][1] = __builtin_amdgcn_mfma_f32_16x16x32_bf16(af1, bf1, acc[1][1], 0, 0, 0);
        }
    }
#pragma unroll
    for (int ms = 0; ms < 2; ++ms)
#pragma unroll
        for (int ns = 0; ns < 2; ++ns)
#pragma unroll
            for (int r = 0; r < 4; ++r) {
                int row = m0b + wr + (ms << 4) + (quad << 2) + r;
                int col = n0b + wc + (ns << 4) + t;
                float v2 = acc[ms][ns][r];
                if (bias) v2 += bias[col];
                if (act == 1) v2 = 0.5f * v2 * (1.f + erff(v2 * 0.70710678118654752f));
                if (resid) v2 += resid[(size_t)row * N + col];
                if (out_f32) ((float*)outp)[(size_t)row * N + col] = v2;
                else ((short*)outp)[(size_t)row * N + col] = f2bs(v2);
            }
}

// ---------------------------------------------------------------------------
// 128x128-tile bf16 MFMA GEMM (QKV & FFN1). uadd: if non-null, cols<512 get
// v = 0.125*(acc + uadd[col])  (fused q-scale + u-fold for QKV).
// ---------------------------------------------------------------------------
__global__ __launch_bounds__(256) void gemm128(
    const short* __restrict__ A, const short* __restrict__ Bt,
    const float* __restrict__ bias, const float* __restrict__ uadd,
    void* __restrict__ outp, int M, int N, int K, int act)
{
    __shared__ __align__(16) short Al[128 * 72];
    __shared__ __align__(16) short Bl[128 * 72];
    int tid = threadIdx.x;
    int w = tid >> 6, lane = tid & 63, quad = lane >> 4, t = lane & 15;
    int m0b = blockIdx.y << 7, n0b = blockIdx.x << 7;
    int wm = (w >> 1) << 6, wn = (w & 1) << 6;
    f32x4 acc[4][4] = {};
    for (int kb = 0; kb < K; kb += 64) {
        __syncthreads();
#pragma unroll
        for (int it = 0; it < 4; ++it) {
            int c = tid + (it << 8);
            int r = c >> 3, c8 = (c & 7) << 3;
            *(bf16x8*)&Al[r * 72 + c8] = *(const bf16x8*)&A[(size_t)(m0b + r) * K + kb + c8];
            *(bf16x8*)&Bl[r * 72 + c8] = *(const bf16x8*)&Bt[(size_t)(n0b + r) * K + kb + c8];
        }
        __syncthreads();
#pragma unroll
        for (int ks = 0; ks < 2; ++ks) {
            bf16x8 af[4], bf[4];
#pragma unroll
            for (int ms = 0; ms < 4; ++ms)
                af[ms] = *(bf16x8*)&Al[(wm + ms * 16 + t) * 72 + (ks << 5) + (quad << 3)];
#pragma unroll
            for (int ns = 0; ns < 4; ++ns)
                bf[ns] = *(bf16x8*)&Bl[(wn + ns * 16 + t) * 72 + (ks << 5) + (quad << 3)];
#pragma unroll
            for (int ms = 0; ms < 4; ++ms)
#pragma unroll
                for (int ns = 0; ns < 4; ++ns)
                    acc[ms][ns] = __builtin_amdgcn_mfma_f32_16x16x32_bf16(af[ms], bf[ns], acc[ms][ns], 0, 0, 0);
        }
    }
#pragma unroll
    for (int ms = 0; ms < 4; ++ms)
#pragma unroll
        for (int ns = 0; ns < 4; ++ns)
#pragma unroll
            for (int r = 0; r < 4; ++r) {
                int row = m0b + wm + ms * 16 + (quad << 2) + r;
                int col = n0b + wn + ns * 16 + t;
                float v2 = acc[ms][ns][r];
                if (uadd && col < 512) v2 = 0.125f * (v2 + uadd[col]);
                if (bias) v2 += bias[col];
                if (act == 1) v2 = 0.5f * v2 * (1.f + erff(v2 * 0.70710678118654752f));
                ((short*)outp)[(size_t)row * N + col] = f2bs(v2);
            }
}

// ---------------------------------------------------------------------------
// qsuf: per row, qw suffix sums folded with VU/VS into the final bias table
// Tg[row][h][35] (fp32, global). s<17: SU+SS, 17..33: SU-SS, 34: SU.
// ---------------------------------------------------------------------------
__global__ __launch_bounds__(256) void qsuf_kernel(
    const short* __restrict__ qkv, const float* __restrict__ wpos,
    const float* __restrict__ VU, const float* __restrict__ VS,
    float* __restrict__ Tg)
{
    __shared__ float qrow[512];
    __shared__ float qw[256];
    __shared__ float sU[136], sS[136];
    int row = blockIdx.x, tid = threadIdx.x;
    const short* base = qkv + (size_t)row * 1792;
    qrow[tid]       = bs2f(base[tid]);
    qrow[tid + 256] = bs2f(base[tid + 256]);
    __syncthreads();
    int h = tid >> 5, n = tid & 31;
    float acc = 0.f;
    for (int d = 0; d < DK_; ++d)
        acc += qrow[h * DK_ + d] * wpos[(h * DK_ + d) * NPOS_ + n];
    qw[tid] = acc;
    __syncthreads();
    if (tid < 136) {
        int hh = tid / 17, m = tid % 17;
        float su = 0.f, ss = 0.f;
        for (int t2 = m; t2 < 16; ++t2) { su += qw[hh * NPOS_ + t2]; ss += qw[hh * NPOS_ + 16 + t2]; }
        sU[tid] = su + VU[tid];
        sS[tid] = ss + VS[tid];
    }
    __syncthreads();
    if (tid < 280) {
        int h2 = tid / 35, s = tid % 35;
        int m = s < 17 ? s : (s < 34 ? s - 17 : 0);
        float su = sU[h2 * 17 + m], ss = sS[h2 * 17 + m];
        Tg[(size_t)row * 280 + tid] = s < 17 ? su + ss : (s < 34 ? su - ss : su);
    }
}

// ---------------------------------------------------------------------------
// vtrans: V section of qkv -> vT[bh][dv][j]  (per-head transposed V)
// ---------------------------------------------------------------------------
__global__ __launch_bounds__(256) void vtrans_kernel(
    const short* __restrict__ qkv, short* __restrict__ vT)
{
    __shared__ __align__(16) short T[64 * 104];
    int tid = threadIdx.x;
    int bh = blockIdx.y, b = bh >> 3, h = bh & 7;
    int j0 = blockIdx.x << 6;
#pragma unroll
    for (int it = 0; it < 3; ++it) {
        int idx = tid + (it << 8);
        int row = idx / 12, c8 = (idx % 12) << 3;
        *(bf16x8*)&T[row * 104 + c8] =
            *(const bf16x8*)&qkv[(size_t)(b * L_ + j0 + row) * 1792 + 1024 + h * DV_ + c8];
    }
    __syncthreads();
#pragma unroll
    for (int it = 0; it < 3; ++it) {
        int dv = (tid & 31) + (it << 5);
        int j8 = ((tid >> 5) & 7) << 3;
        bf16x8 o;
#pragma unroll
        for (int e = 0; e < 8; ++e) o[e] = __builtin_bit_cast(__bf16, T[(j8 + e) * 104 + dv]);
        *(bf16x8*)&vT[((size_t)bh * DV_ + dv) * L_ + j0 + j8] = o;
    }
}

// ---------------------------------------------------------------------------
// Flash attention v9: 32 Q-rows/block (wave pairs split the 64-j tile),
// K/V fragments streamed straight from global (L1/L2 — no LDS staging, no
// j-loop barriers), bias tables in LDS, same-wave P round-trip.
// Grid: (L/32 = 64, B*H = 16) = 1024 blocks -> 4 blocks/CU.
// ---------------------------------------------------------------------------
__global__ __launch_bounds__(256, 4) void flash_kernel(
    const short* __restrict__ qkv, const short* __restrict__ vT,
    const float* __restrict__ Tg, const unsigned char* __restrict__ sidx_g,
    short* __restrict__ ao)
{
    __shared__ __align__(16) char arena[24832];
    short* Pl = (short*)arena;                         // [32][72] = 4608 B
    float* Tt = (float*)(arena + 4608);                // [32][36] = 4608 B
    unsigned char* sidxl = (unsigned char*)(arena + 9216);  // 4096 B
    float* Obuf = (float*)arena;                       // [4][16][96] = 24576 B (post-loop)
    float* Lbuf = (float*)(arena + 24576);             // [4][16] = 256 B

    int tid = threadIdx.x, w = tid >> 6, lane = tid & 63, quad = lane >> 4, t = lane & 15;
    int bh = blockIdx.y, b = bh >> 3, h = bh & 7;
    int i0 = blockIdx.x << 5;
    int p = w >> 1, hf = w & 1;

    for (int idx = tid; idx < 32 * 35; idx += 256) {
        int il = idx / 35, s = idx % 35;
        Tt[il * 36 + s] = Tg[(size_t)(b * L_ + i0 + il) * 280 + h * 35 + s];
    }
    for (int idx = tid; idx < 4095; idx += 256) sidxl[idx] = sidx_g[idx];
    __syncthreads();

    const short* qbase = qkv + (size_t)(b * L_ + i0 + p * 16 + t) * 1792 + h * DK_;
    bf16x8 qf0 = *(const bf16x8*)(qbase + (quad << 3));
    bf16x8 qf1 = *(const bf16x8*)(qbase + 32 + (quad << 3));

    f32x4 O[6] = {};
    float ls[4] = {0.f, 0.f, 0.f, 0.f};

    const short* kbase = qkv + (size_t)b * L_ * 1792 + 512 + h * DK_;
    const short* vbase = vT + (size_t)bh * DV_ * L_;

    for (int j0 = 0; j0 < L_; j0 += 64) {
        int jh = j0 + (hf << 5);
        f32x4 S[2];
#pragma unroll
        for (int ct = 0; ct < 2; ++ct) {
            const short* kr = kbase + (size_t)(jh + ct * 16 + t) * 1792;
            bf16x8 b0 = *(const bf16x8*)(kr + (quad << 3));
            bf16x8 b1 = *(const bf16x8*)(kr + 32 + (quad << 3));
            f32x4 z = {};
            z = __builtin_amdgcn_mfma_f32_16x16x32_bf16(qf0, b0, z, 0, 0, 0);
            S[ct] = __builtin_amdgcn_mfma_f32_16x16x32_bf16(qf1, b1, z, 0, 0, 0);
        }
#pragma unroll
        for (int r = 0; r < 4; ++r) {
            int il = p * 16 + (quad << 2) + r;
            int i = i0 + il;
            const float* Trow = &Tt[il * 36];
#pragma unroll
            for (int ct = 0; ct < 2; ++ct) {
                int j = jh + ct * 16 + t;
                int s = sidxl[j - i + 2047];
                float pv = __expf(S[ct][r] + Trow[s]);
                short pb = f2bs(pv);
                ls[r] += bs2f(pb);
                Pl[il * 72 + (hf << 5) + ct * 16 + t] = pb;
            }
        }
        bf16x8 pa = *(bf16x8*)&Pl[(p * 16 + t) * 72 + (hf << 5) + (quad << 3)];
#pragma unroll
        for (int dv = 0; dv < 6; ++dv) {
            bf16x8 vb = *(const bf16x8*)&vbase[(size_t)(dv * 16 + t) * L_ + jh + (quad << 3)];
            O[dv] = __builtin_amdgcn_mfma_f32_16x16x32_bf16(pa, vb, O[dv], 0, 0, 0);
        }
    }
#pragma unroll
    for (int r = 0; r < 4; ++r) {
        ls[r] += __shfl_xor(ls[r], 1);
        ls[r] += __shfl_xor(ls[r], 2);
        ls[r] += __shfl_xor(ls[r], 4);
        ls[r] += __shfl_xor(ls[r], 8);
    }
    __syncthreads();   // everyone done with Pl/Tt/sidxl; arena becomes Obuf/Lbuf
#pragma unroll
    for (int dv = 0; dv < 6; ++dv)
#pragma unroll
        for (int r = 0; r < 4; ++r)
            Obuf[w * 1536 + ((quad << 2) + r) * 96 + dv * 16 + t] = O[dv][r];
    if (t == 0) {
#pragma unroll
        for (int r = 0; r < 4; ++r) Lbuf[w * 16 + (quad << 2) + r] = ls[r];
    }
    __syncthreads();
    for (int idx = tid; idx < 32 * 96; idx += 256) {
        int row = idx / 96, col = idx % 96;
        int pr2 = row >> 4, rl = row & 15;
        float o = Obuf[(2 * pr2) * 1536 + rl * 96 + col] + Obuf[(2 * pr2 + 1) * 1536 + rl * 96 + col];
        float l = Lbuf[(2 * pr2) * 16 + rl] + Lbuf[(2 * pr2 + 1) * 16 + rl];
        ao[(size_t)(b * L_ + i0 + row) * D_ + h * DV_ + col] = f2bs(o / l);
    }
}

// ---------------------------------------------------------------------------
extern "C" void kernel_launch(void* const* d_in, const int* in_sizes, int n_in,
                              void* d_out, int out_size, void* d_ws, size_t ws_size,
                              hipStream_t stream)
{
    const float* x    = (const float*)d_in[0];
    const float* n1w  = (const float*)d_in[1];
    const float* n2w  = (const float*)d_in[2];
    const float* wq   = (const float*)d_in[3];
    const float* wk   = (const float*)d_in[4];
    const float* wv   = (const float*)d_in[5];
    const float* wo   = (const float*)d_in[6];
    const float* bo   = (const float*)d_in[7];
    const float* up   = (const float*)d_in[8];
    const float* vp   = (const float*)d_in[9];
    const float* wpos = (const float*)d_in[10];
    const float* w1   = (const float*)d_in[11];
    const float* b1   = (const float*)d_in[12];
    const float* w2   = (const float*)d_in[13];
    const float* b2   = (const float*)d_in[14];

    char* ws = (char*)d_ws;
    short* h1   = (short*)(ws + 0);         // [4096,768] bf16
    short* qkv  = (short*)(ws + 6291456);   // [4096,1792] bf16, ends 20971520
    float* Tg   = (float*)(ws + 20971520);  // [4096,8,35] f32, ends 25559040
    float* VUg  = (float*)(ws + 25559040);
    float* VSg  = (float*)(ws + 25560064);
    unsigned char* sidx = (unsigned char*)(ws + 25561088);  // [4096]
    short* ao   = (short*)(ws + 25569280);  // [4096,768] bf16
    float* x2   = (float*)(ws + 31860736);  // [4096,768] f32, ends 44443648
    short* vT   = (short*)(ws + 31860736);  // [16,96,2048] bf16 overlays x2 (dead before wo-gemm)
    short* wqkvT= (short*)(ws + 44443648);  // [1792,768] bf16, ends 47196160
    short* woT  = (short*)(ws + 47196160);  // [768,768]
    short* w1T  = (short*)(ws + 48375808);  // [1536,768]
    short* w2T  = (short*)(ws + 50735104);  // [768,1536], ends 53094400
    short* f1   = (short*)(ws + 0);         // [4096,1536] overlays h1+qkv head (dead)
    short* h2n  = (short*)(ws + 14680064);  // [4096,768] overlays qkv tail (dead)

    prep_kernel<<<1057, 256, 0, stream>>>(wq, wk, wv, wo, w1, w2, vp, up, wpos,
                                          wqkvT, woT, w1T, w2T, sidx, VUg, VSg);
    rmsnorm_kernel<<<4096, 256, 0, stream>>>(x, n1w, h1);
    gemm128<<<dim3(14, 32), 256, 0, stream>>>(h1, wqkvT, nullptr, up, qkv, 4096, 1792, 768, 0);
    qsuf_kernel<<<4096, 256, 0, stream>>>(qkv, wpos, VUg, VSg, Tg);
    vtrans_kernel<<<dim3(32, 16), 256, 0, stream>>>(qkv, vT);
    flash_kernel<<<dim3(64, 16), 256, 0, stream>>>(qkv, vT, Tg, sidx, ao);
    gemm64<<<dim3(12, 64), 256, 0, stream>>>(ao, woT, bo, x, x2, 4096, 768, 768, 0, 1);
    rmsnorm_kernel<<<4096, 256, 0, stream>>>(x2, n2w, h2n);
    gemm128<<<dim3(12, 32), 256, 0, stream>>>(h2n, w1T, b1, nullptr, f1, 4096, 1536, 768, 1);
    gemm64<<<dim3(12, 64), 256, 0, stream>>>(f1, w2T, b2, x2, d_out, 4096, 768, 1536, 0, 1);
}

// Round 10
// 354.563 us; speedup vs baseline: 1.1948x; 1.1948x over previous
//
#include <hip/hip_runtime.h>

#define B_ 2
#define L_ 2048
#define D_ 768
#define H_ 8
#define DK_ 64
#define DV_ 96
#define NPOS_ 32

typedef __attribute__((ext_vector_type(8))) __bf16 bf16x8;
typedef __attribute__((ext_vector_type(4))) float f32x4;

static __device__ __forceinline__ float bs2f(short s) {
    return (float)__builtin_bit_cast(__bf16, s);
}
static __device__ __forceinline__ short f2bs(float f) {
    return __builtin_bit_cast(short, (__bf16)f);
}

// ---------------------------------------------------------------------------
// prep: blocks 0..1055 transpose+convert all weights (wq/wk/wv packed into
// wqkvT[1792][768]); block 1056 builds sidx table + adjusted VU/VS tables:
// VU = 0.125*(suffix(v.wpos) - suffix(u.wpos))   [u-part corrects the q+u fold]
// sidx[d+2047]: s<17 -> d>0 (SU+SS), 17..33 -> d<0 (SU-SS), 34 -> d==0 (SU).
// ---------------------------------------------------------------------------
__global__ __launch_bounds__(256) void prep_kernel(
    const float* __restrict__ wq, const float* __restrict__ wk,
    const float* __restrict__ wv, const float* __restrict__ wo,
    const float* __restrict__ w1, const float* __restrict__ w2,
    const float* __restrict__ vparam, const float* __restrict__ uparam,
    const float* __restrict__ wpos,
    short* __restrict__ wqkvT, short* __restrict__ woT,
    short* __restrict__ w1T, short* __restrict__ w2T,
    unsigned char* __restrict__ sidx, float* __restrict__ VU, float* __restrict__ VS)
{
    __shared__ short T[64][66];
    __shared__ float vw[H_ * NPOS_];
    __shared__ float uw[H_ * NPOS_];
    int blk = blockIdx.x, tid = threadIdx.x;
    if (blk < 1056) {
        const float* W; short* Wt; int K, N, bx, by;
        if (blk < 96)       { W = wq; Wt = wqkvT;              K = 768;  N = 512;  int b = blk;       bx = b % 8;  by = b / 8; }
        else if (blk < 192) { W = wk; Wt = wqkvT + 512 * 768;  K = 768;  N = 512;  int b = blk - 96;  bx = b % 8;  by = b / 8; }
        else if (blk < 336) { W = wv; Wt = wqkvT + 1024 * 768; K = 768;  N = 768;  int b = blk - 192; bx = b % 12; by = b / 12; }
        else if (blk < 480) { W = wo; Wt = woT;                K = 768;  N = 768;  int b = blk - 336; bx = b % 12; by = b / 12; }
        else if (blk < 768) { W = w1; Wt = w1T;                K = 768;  N = 1536; int b = blk - 480; bx = b % 24; by = b / 24; }
        else                { W = w2; Wt = w2T;                K = 1536; N = 768;  int b = blk - 768; bx = b % 12; by = b / 12; }
        int n0 = bx << 6, k0 = by << 6;
        for (int idx = tid; idx < 4096; idx += 256) {
            int r = idx >> 6, c = idx & 63;
            T[c][r] = f2bs(W[(size_t)(k0 + r) * N + n0 + c]);
        }
        __syncthreads();
        for (int idx = tid; idx < 4096; idx += 256) {
            int r = idx >> 6, c = idx & 63;
            Wt[(size_t)(n0 + r) * K + k0 + c] = T[r][c];
        }
    } else {
        float pr = expf(logf((L_ + 1) / 2.0f) / (NPOS_ / 2));
        for (int idx = tid; idx < 4095; idx += 256) {
            int d = idx - 2047;
            int ad = d < 0 ? -d : d;
            int c = 0;
            for (int m = 1; m <= NPOS_ / 2; ++m) {
                float cw = powf(pr, (float)m);
                if (cw < (float)ad) c++;
            }
            sidx[idx] = (unsigned char)(d > 0 ? c : (d < 0 ? 17 + c : 34));
        }
        {
            int h = tid >> 5, n = tid & 31;
            float av = 0.f, au = 0.f;
            for (int d = 0; d < DK_; ++d) {
                float wp = wpos[(h * DK_ + d) * NPOS_ + n];
                av += vparam[h * DK_ + d] * wp;
                au += uparam[h * DK_ + d] * wp;
            }
            vw[tid] = av;
            uw[tid] = au;
        }
        __syncthreads();
        if (tid < H_ * 17) {
            int h = tid / 17, m = tid % 17;
            float su = 0.f, ss = 0.f;
            for (int t2 = m; t2 < 16; ++t2) {
                su += vw[h * NPOS_ + t2] - uw[h * NPOS_ + t2];
                ss += vw[h * NPOS_ + 16 + t2] - uw[h * NPOS_ + 16 + t2];
            }
            VU[h * 17 + m] = su * 0.125f;
            VS[h * 17 + m] = ss * 0.125f;
        }
    }
}

// ---------------------------------------------------------------------------
// RMSNorm (row of 768), fp32 in, bf16 out
// ---------------------------------------------------------------------------
__global__ __launch_bounds__(256) void rmsnorm_kernel(
    const float* __restrict__ x, const float* __restrict__ wgt, short* __restrict__ out)
{
    int row = blockIdx.x, tid = threadIdx.x;
    __shared__ float red[4];
    const float* xr = x + (size_t)row * D_;
    float ss = 0.f;
    for (int c = tid; c < D_; c += 256) { float f = xr[c]; ss += f * f; }
    for (int msk = 1; msk < 64; msk <<= 1) ss += __shfl_xor(ss, msk);
    if ((tid & 63) == 0) red[tid >> 6] = ss;
    __syncthreads();
    float tot = red[0] + red[1] + red[2] + red[3];
    float sc = rsqrtf(tot * (1.f / D_) + 1e-5f);
    for (int c = tid; c < D_; c += 256)
        out[(size_t)row * D_ + c] = f2bs(xr[c] * sc * wgt[c]);
}

// ---------------------------------------------------------------------------
// 64x64-tile bf16 MFMA GEMM (N=768 shapes: wo, FFN2)
// ---------------------------------------------------------------------------
__global__ __launch_bounds__(256) void gemm64(
    const short* __restrict__ A, const short* __restrict__ Bt,
    const float* __restrict__ bias, const float* __restrict__ resid,
    void* __restrict__ outp,
    int M, int N, int K, int act, int out_f32)
{
    __shared__ __align__(16) short Al[64 * 72];
    __shared__ __align__(16) short Bl[64 * 72];
    int tid = threadIdx.x;
    int w = tid >> 6, lane = tid & 63, quad = lane >> 4, t = lane & 15;
    int m0b = blockIdx.y << 6, n0b = blockIdx.x << 6;
    int wr = (w >> 1) << 5, wc = (w & 1) << 5;
    f32x4 acc[2][2] = {};
    for (int kb = 0; kb < K; kb += 64) {
        __syncthreads();
#pragma unroll
        for (int it = 0; it < 2; ++it) {
            int idx = tid + (it << 8);
            int r = idx >> 3, c8 = (idx & 7) << 3;
            *(bf16x8*)&Al[r * 72 + c8] = *(const bf16x8*)&A[(size_t)(m0b + r) * K + kb + c8];
            *(bf16x8*)&Bl[r * 72 + c8] = *(const bf16x8*)&Bt[(size_t)(n0b + r) * K + kb + c8];
        }
        __syncthreads();
#pragma unroll
        for (int ks = 0; ks < 2; ++ks) {
            bf16x8 af0 = *(bf16x8*)&Al[(wr + t) * 72 + (ks << 5) + (quad << 3)];
            bf16x8 af1 = *(bf16x8*)&Al[(wr + 16 + t) * 72 + (ks << 5) + (quad << 3)];
            bf16x8 bf0 = *(bf16x8*)&Bl[(wc + t) * 72 + (ks << 5) + (quad << 3)];
            bf16x8 bf1 = *(bf16x8*)&Bl[(wc + 16 + t) * 72 + (ks << 5) + (quad << 3)];
            acc[0][0] = __builtin_amdgcn_mfma_f32_16x16x32_bf16(af0, bf0, acc[0][0], 0, 0, 0);
            acc[0][1] = __builtin_amdgcn_mfma_f32_16x16x32_bf16(af0, bf1, acc[0][1], 0, 0, 0);
            acc[1][0] = __builtin_amdgcn_mfma_f32_16x16x32_bf16(af1, bf0, acc[1][0], 0, 0, 0);
            acc[1][1] = __builtin_amdgcn_mfma_f32_16x16x32_bf16(af1, bf1, acc[1][1], 0, 0, 0);
        }
    }
#pragma unroll
    for (int ms = 0; ms < 2; ++ms)
#pragma unroll
        for (int ns = 0; ns < 2; ++ns)
#pragma unroll
            for (int r = 0; r < 4; ++r) {
                int row = m0b + wr + (ms << 4) + (quad << 2) + r;
                int col = n0b + wc + (ns << 4) + t;
                float v2 = acc[ms][ns][r];
                if (bias) v2 += bias[col];
                if (act == 1) v2 = 0.5f * v2 * (1.f + erff(v2 * 0.70710678118654752f));
                if (resid) v2 += resid[(size_t)row * N + col];
                if (out_f32) ((float*)outp)[(size_t)row * N + col] = v2;
                else ((short*)outp)[(size_t)row * N + col] = f2bs(v2);
            }
}

// ---------------------------------------------------------------------------
// 128x128-tile bf16 MFMA GEMM (QKV & FFN1). uadd: if non-null, cols<512 get
// v = 0.125*(acc + uadd[col])  (fused q-scale + u-fold for QKV).
// ---------------------------------------------------------------------------
__global__ __launch_bounds__(256) void gemm128(
    const short* __restrict__ A, const short* __restrict__ Bt,
    const float* __restrict__ bias, const float* __restrict__ uadd,
    void* __restrict__ outp, int M, int N, int K, int act)
{
    __shared__ __align__(16) short Al[128 * 72];
    __shared__ __align__(16) short Bl[128 * 72];
    int tid = threadIdx.x;
    int w = tid >> 6, lane = tid & 63, quad = lane >> 4, t = lane & 15;
    int m0b = blockIdx.y << 7, n0b = blockIdx.x << 7;
    int wm = (w >> 1) << 6, wn = (w & 1) << 6;
    f32x4 acc[4][4] = {};
    for (int kb = 0; kb < K; kb += 64) {
        __syncthreads();
#pragma unroll
        for (int it = 0; it < 4; ++it) {
            int c = tid + (it << 8);
            int r = c >> 3, c8 = (c & 7) << 3;
            *(bf16x8*)&Al[r * 72 + c8] = *(const bf16x8*)&A[(size_t)(m0b + r) * K + kb + c8];
            *(bf16x8*)&Bl[r * 72 + c8] = *(const bf16x8*)&Bt[(size_t)(n0b + r) * K + kb + c8];
        }
        __syncthreads();
#pragma unroll
        for (int ks = 0; ks < 2; ++ks) {
            bf16x8 af[4], bf[4];
#pragma unroll
            for (int ms = 0; ms < 4; ++ms)
                af[ms] = *(bf16x8*)&Al[(wm + ms * 16 + t) * 72 + (ks << 5) + (quad << 3)];
#pragma unroll
            for (int ns = 0; ns < 4; ++ns)
                bf[ns] = *(bf16x8*)&Bl[(wn + ns * 16 + t) * 72 + (ks << 5) + (quad << 3)];
#pragma unroll
            for (int ms = 0; ms < 4; ++ms)
#pragma unroll
                for (int ns = 0; ns < 4; ++ns)
                    acc[ms][ns] = __builtin_amdgcn_mfma_f32_16x16x32_bf16(af[ms], bf[ns], acc[ms][ns], 0, 0, 0);
        }
    }
#pragma unroll
    for (int ms = 0; ms < 4; ++ms)
#pragma unroll
        for (int ns = 0; ns < 4; ++ns)
#pragma unroll
            for (int r = 0; r < 4; ++r) {
                int row = m0b + wm + ms * 16 + (quad << 2) + r;
                int col = n0b + wn + ns * 16 + t;
                float v2 = acc[ms][ns][r];
                if (uadd && col < 512) v2 = 0.125f * (v2 + uadd[col]);
                if (bias) v2 += bias[col];
                if (act == 1) v2 = 0.5f * v2 * (1.f + erff(v2 * 0.70710678118654752f));
                ((short*)outp)[(size_t)row * N + col] = f2bs(v2);
            }
}

// ---------------------------------------------------------------------------
// qsuf: per row, qw suffix sums folded with VU/VS into the final bias table
// Tg[row][h][35] (fp32, global). s<17: SU+SS, 17..33: SU-SS, 34: SU.
// ---------------------------------------------------------------------------
__global__ __launch_bounds__(256) void qsuf_kernel(
    const short* __restrict__ qkv, const float* __restrict__ wpos,
    const float* __restrict__ VU, const float* __restrict__ VS,
    float* __restrict__ Tg)
{
    __shared__ float qrow[512];
    __shared__ float qw[256];
    __shared__ float sU[136], sS[136];
    int row = blockIdx.x, tid = threadIdx.x;
    const short* base = qkv + (size_t)row * 1792;
    qrow[tid]       = bs2f(base[tid]);
    qrow[tid + 256] = bs2f(base[tid + 256]);
    __syncthreads();
    int h = tid >> 5, n = tid & 31;
    float acc = 0.f;
    for (int d = 0; d < DK_; ++d)
        acc += qrow[h * DK_ + d] * wpos[(h * DK_ + d) * NPOS_ + n];
    qw[tid] = acc;
    __syncthreads();
    if (tid < 136) {
        int hh = tid / 17, m = tid % 17;
        float su = 0.f, ss = 0.f;
        for (int t2 = m; t2 < 16; ++t2) { su += qw[hh * NPOS_ + t2]; ss += qw[hh * NPOS_ + 16 + t2]; }
        sU[tid] = su + VU[tid];
        sS[tid] = ss + VS[tid];
    }
    __syncthreads();
    if (tid < 280) {
        int h2 = tid / 35, s = tid % 35;
        int m = s < 17 ? s : (s < 34 ? s - 17 : 0);
        float su = sU[h2 * 17 + m], ss = sS[h2 * 17 + m];
        Tg[(size_t)row * 280 + tid] = s < 17 ? su + ss : (s < 34 ? su - ss : su);
    }
}

// ---------------------------------------------------------------------------
// vtrans: V section of qkv -> vT[bh][dv][j]  (per-head transposed V)
// ---------------------------------------------------------------------------
__global__ __launch_bounds__(256) void vtrans_kernel(
    const short* __restrict__ qkv, short* __restrict__ vT)
{
    __shared__ __align__(16) short T[64 * 104];
    int tid = threadIdx.x;
    int bh = blockIdx.y, b = bh >> 3, h = bh & 7;
    int j0 = blockIdx.x << 6;
#pragma unroll
    for (int it = 0; it < 3; ++it) {
        int idx = tid + (it << 8);
        int row = idx / 12, c8 = (idx % 12) << 3;
        *(bf16x8*)&T[row * 104 + c8] =
            *(const bf16x8*)&qkv[(size_t)(b * L_ + j0 + row) * 1792 + 1024 + h * DV_ + c8];
    }
    __syncthreads();
#pragma unroll
    for (int it = 0; it < 3; ++it) {
        int dv = (tid & 31) + (it << 5);
        int j8 = ((tid >> 5) & 7) << 3;
        bf16x8 o;
#pragma unroll
        for (int e = 0; e < 8; ++e) o[e] = __builtin_bit_cast(__bf16, T[(j8 + e) * 104 + dv]);
        *(bf16x8*)&vT[((size_t)bh * DV_ + dv) * L_ + j0 + j8] = o;
    }
}

// ---------------------------------------------------------------------------
// Flash attention v10 = round-7 structure (128-j tiles, register prefetch,
// LDS bias tables) + V staged from vT (b128, no scalar scatter) + padded
// strides 140 (conflict-free V-frag reads and P writes).
// Grid: (L/64 = 32, B*H = 16), 4 waves/block, 2 blocks/CU.
// ---------------------------------------------------------------------------
__global__ __launch_bounds__(256) void flash_kernel(
    const short* __restrict__ qkv, const short* __restrict__ vT,
    const float* __restrict__ Tg, const unsigned char* __restrict__ sidx_g,
    short* __restrict__ ao)
{
    __shared__ __align__(16) short Kl[128 * 72];   // [j][d]
    __shared__ __align__(16) short Vt[96 * 140];   // [dv][j]
    __shared__ __align__(16) short Pl[64 * 140];   // [il][j]
    __shared__ float Tt[64 * 36];
    __shared__ unsigned char sidxl[4096];
    int tid = threadIdx.x, w = tid >> 6, lane = tid & 63, quad = lane >> 4, t = lane & 15;
    int bh = blockIdx.y, b = bh >> 3, h = bh & 7;
    int i0 = blockIdx.x << 6;

    for (int idx = tid; idx < 64 * 35; idx += 256) {
        int il = idx / 35, s = idx % 35;
        Tt[il * 36 + s] = Tg[(size_t)(b * L_ + i0 + il) * 280 + h * 35 + s];
    }
    for (int idx = tid; idx < 4095; idx += 256) sidxl[idx] = sidx_g[idx];

    int iq = i0 + w * 16 + t;
    const short* qbase = qkv + (size_t)(b * L_ + iq) * 1792 + h * DK_;
    bf16x8 qf0 = *(const bf16x8*)(qbase + (quad << 3));
    bf16x8 qf1 = *(const bf16x8*)(qbase + 32 + (quad << 3));

    f32x4 O[6] = {};
    float lsum[4] = {0.f, 0.f, 0.f, 0.f};

    // prefetch mappings
    int kr = tid >> 3, kc = (tid & 7) << 3;        // K: rows kr+32it, cols kc..kc+7
    int vdv = tid >> 4, vj8 = (tid & 15) << 3;     // V: idx=tid+256it -> dv=idx/16, j8=(idx%16)*8
    bf16x8 kpre[4], vpre[6];
    {
        const short* kb0 = &qkv[(size_t)(b * L_ + kr) * 1792 + 512 + h * DK_ + kc];
#pragma unroll
        for (int it = 0; it < 4; ++it)
            kpre[it] = *(const bf16x8*)(kb0 + (size_t)(it << 5) * 1792);
        const short* vb0 = &vT[(size_t)bh * DV_ * L_];
#pragma unroll
        for (int it = 0; it < 6; ++it)
            vpre[it] = *(const bf16x8*)(vb0 + (size_t)(vdv + (it << 4)) * L_ + vj8);
    }

    for (int j0 = 0; j0 < L_; j0 += 128) {
        __syncthreads();
#pragma unroll
        for (int it = 0; it < 4; ++it)
            *(bf16x8*)&Kl[(kr + (it << 5)) * 72 + kc] = kpre[it];
#pragma unroll
        for (int it = 0; it < 6; ++it)
            *(bf16x8*)&Vt[(vdv + (it << 4)) * 140 + vj8] = vpre[it];
        {
            int jn = (j0 + 128 < L_) ? j0 + 128 : 0;
            const short* kb0 = &qkv[(size_t)(b * L_ + jn + kr) * 1792 + 512 + h * DK_ + kc];
#pragma unroll
            for (int it = 0; it < 4; ++it)
                kpre[it] = *(const bf16x8*)(kb0 + (size_t)(it << 5) * 1792);
            const short* vb0 = &vT[(size_t)bh * DV_ * L_ + jn];
#pragma unroll
            for (int it = 0; it < 6; ++it)
                vpre[it] = *(const bf16x8*)(vb0 + (size_t)(vdv + (it << 4)) * L_ + vj8);
        }
        __syncthreads();

        f32x4 S[8];
#pragma unroll
        for (int ct = 0; ct < 8; ++ct) {
            bf16x8 b0 = *(bf16x8*)&Kl[(ct * 16 + t) * 72 + (quad << 3)];
            bf16x8 b1 = *(bf16x8*)&Kl[(ct * 16 + t) * 72 + 32 + (quad << 3)];
            f32x4 z = {};
            z = __builtin_amdgcn_mfma_f32_16x16x32_bf16(qf0, b0, z, 0, 0, 0);
            S[ct] = __builtin_amdgcn_mfma_f32_16x16x32_bf16(qf1, b1, z, 0, 0, 0);
        }
#pragma unroll
        for (int r = 0; r < 4; ++r) {
            int il = w * 16 + (quad << 2) + r;
            int i = i0 + il;
            const float* Trow = &Tt[il * 36];
#pragma unroll
            for (int ct = 0; ct < 8; ++ct) {
                int j = j0 + ct * 16 + t;
                int s = sidxl[j - i + 2047];
                float p = __expf(S[ct][r] + Trow[s]);
                short pb = f2bs(p);
                lsum[r] += bs2f(pb);
                Pl[il * 140 + ct * 16 + t] = pb;
            }
        }
#pragma unroll
        for (int ks = 0; ks < 4; ++ks) {
            bf16x8 pa = *(bf16x8*)&Pl[(w * 16 + t) * 140 + (ks << 5) + (quad << 3)];
#pragma unroll
            for (int dv = 0; dv < 6; ++dv) {
                bf16x8 vb = *(bf16x8*)&Vt[(dv * 16 + t) * 140 + (ks << 5) + (quad << 3)];
                O[dv] = __builtin_amdgcn_mfma_f32_16x16x32_bf16(pa, vb, O[dv], 0, 0, 0);
            }
        }
    }
#pragma unroll
    for (int r = 0; r < 4; ++r) {
        float lr = lsum[r];
        lr += __shfl_xor(lr, 1);
        lr += __shfl_xor(lr, 2);
        lr += __shfl_xor(lr, 4);
        lr += __shfl_xor(lr, 8);
        float inv = 1.f / lr;
        int i = i0 + w * 16 + (quad << 2) + r;
        size_t base = (size_t)(b * L_ + i) * D_ + h * DV_;
#pragma unroll
        for (int dv = 0; dv < 6; ++dv) ao[base + dv * 16 + t] = f2bs(O[dv][r] * inv);
    }
}

// ---------------------------------------------------------------------------
extern "C" void kernel_launch(void* const* d_in, const int* in_sizes, int n_in,
                              void* d_out, int out_size, void* d_ws, size_t ws_size,
                              hipStream_t stream)
{
    const float* x    = (const float*)d_in[0];
    const float* n1w  = (const float*)d_in[1];
    const float* n2w  = (const float*)d_in[2];
    const float* wq   = (const float*)d_in[3];
    const float* wk   = (const float*)d_in[4];
    const float* wv   = (const float*)d_in[5];
    const float* wo   = (const float*)d_in[6];
    const float* bo   = (const float*)d_in[7];
    const float* up   = (const float*)d_in[8];
    const float* vp   = (const float*)d_in[9];
    const float* wpos = (const float*)d_in[10];
    const float* w1   = (const float*)d_in[11];
    const float* b1   = (const float*)d_in[12];
    const float* w2   = (const float*)d_in[13];
    const float* b2   = (const float*)d_in[14];

    char* ws = (char*)d_ws;
    short* h1   = (short*)(ws + 0);         // [4096,768] bf16
    short* qkv  = (short*)(ws + 6291456);   // [4096,1792] bf16, ends 20971520
    float* Tg   = (float*)(ws + 20971520);  // [4096,8,35] f32, ends 25559040
    float* VUg  = (float*)(ws + 25559040);
    float* VSg  = (float*)(ws + 25560064);
    unsigned char* sidx = (unsigned char*)(ws + 25561088);  // [4096]
    short* ao   = (short*)(ws + 25569280);  // [4096,768] bf16
    float* x2   = (float*)(ws + 31860736);  // [4096,768] f32, ends 44443648
    short* vT   = (short*)(ws + 31860736);  // [16,96,2048] bf16 overlays x2 (dead before wo-gemm)
    short* wqkvT= (short*)(ws + 44443648);  // [1792,768] bf16, ends 47196160
    short* woT  = (short*)(ws + 47196160);  // [768,768]
    short* w1T  = (short*)(ws + 48375808);  // [1536,768]
    short* w2T  = (short*)(ws + 50735104);  // [768,1536], ends 53094400
    short* f1   = (short*)(ws + 0);         // [4096,1536] overlays h1+qkv head (dead)
    short* h2n  = (short*)(ws + 14680064);  // [4096,768] overlays qkv tail (dead)

    prep_kernel<<<1057, 256, 0, stream>>>(wq, wk, wv, wo, w1, w2, vp, up, wpos,
                                          wqkvT, woT, w1T, w2T, sidx, VUg, VSg);
    rmsnorm_kernel<<<4096, 256, 0, stream>>>(x, n1w, h1);
    gemm128<<<dim3(14, 32), 256, 0, stream>>>(h1, wqkvT, nullptr, up, qkv, 4096, 1792, 768, 0);
    qsuf_kernel<<<4096, 256, 0, stream>>>(qkv, wpos, VUg, VSg, Tg);
    vtrans_kernel<<<dim3(32, 16), 256, 0, stream>>>(qkv, vT);
    flash_kernel<<<dim3(32, 16), 256, 0, stream>>>(qkv, vT, Tg, sidx, ao);
    gemm64<<<dim3(12, 64), 256, 0, stream>>>(ao, woT, bo, x, x2, 4096, 768, 768, 0, 1);
    rmsnorm_kernel<<<4096, 256, 0, stream>>>(x2, n2w, h2n);
    gemm128<<<dim3(12, 32), 256, 0, stream>>>(h2n, w1T, b1, nullptr, f1, 4096, 1536, 768, 1);
    gemm64<<<dim3(12, 64), 256, 0, stream>>>(f1, w2T, b2, x2, d_out, 4096, 768, 1536, 0, 1);
}

// Round 11
// 345.866 us; speedup vs baseline: 1.2248x; 1.0251x over previous
//
#include <hip/hip_runtime.h>

#define B_ 2
#define L_ 2048
#define D_ 768
#define H_ 8
#define DK_ 64
#define DV_ 96
#define NPOS_ 32

typedef __attribute__((ext_vector_type(8))) __bf16 bf16x8;
typedef __attribute__((ext_vector_type(4))) float f32x4;

static __device__ __forceinline__ float bs2f(short s) {
    return (float)__builtin_bit_cast(__bf16, s);
}
static __device__ __forceinline__ short f2bs(float f) {
    return __builtin_bit_cast(short, (__bf16)f);
}

// ---------------------------------------------------------------------------
// prep: blocks 0..1055 transpose+convert all weights (wq/wk/wv packed into
// wqkvT[1792][768]); block 1056 builds sidx table + adjusted VU/VS tables:
// VU = 0.125*(suffix(v.wpos) - suffix(u.wpos))   [u-part corrects the q+u fold]
// sidx[d+2047]: s<17 -> d>0 (SU+SS), 17..33 -> d<0 (SU-SS), 34 -> d==0 (SU).
// ---------------------------------------------------------------------------
__global__ __launch_bounds__(256) void prep_kernel(
    const float* __restrict__ wq, const float* __restrict__ wk,
    const float* __restrict__ wv, const float* __restrict__ wo,
    const float* __restrict__ w1, const float* __restrict__ w2,
    const float* __restrict__ vparam, const float* __restrict__ uparam,
    const float* __restrict__ wpos,
    short* __restrict__ wqkvT, short* __restrict__ woT,
    short* __restrict__ w1T, short* __restrict__ w2T,
    unsigned char* __restrict__ sidx, float* __restrict__ VU, float* __restrict__ VS)
{
    __shared__ short T[64][66];
    __shared__ float vw[H_ * NPOS_];
    __shared__ float uw[H_ * NPOS_];
    int blk = blockIdx.x, tid = threadIdx.x;
    if (blk < 1056) {
        const float* W; short* Wt; int K, N, bx, by;
        if (blk < 96)       { W = wq; Wt = wqkvT;              K = 768;  N = 512;  int b = blk;       bx = b % 8;  by = b / 8; }
        else if (blk < 192) { W = wk; Wt = wqkvT + 512 * 768;  K = 768;  N = 512;  int b = blk - 96;  bx = b % 8;  by = b / 8; }
        else if (blk < 336) { W = wv; Wt = wqkvT + 1024 * 768; K = 768;  N = 768;  int b = blk - 192; bx = b % 12; by = b / 12; }
        else if (blk < 480) { W = wo; Wt = woT;                K = 768;  N = 768;  int b = blk - 336; bx = b % 12; by = b / 12; }
        else if (blk < 768) { W = w1; Wt = w1T;                K = 768;  N = 1536; int b = blk - 480; bx = b % 24; by = b / 24; }
        else                { W = w2; Wt = w2T;                K = 1536; N = 768;  int b = blk - 768; bx = b % 12; by = b / 12; }
        int n0 = bx << 6, k0 = by << 6;
        for (int idx = tid; idx < 4096; idx += 256) {
            int r = idx >> 6, c = idx & 63;
            T[c][r] = f2bs(W[(size_t)(k0 + r) * N + n0 + c]);
        }
        __syncthreads();
        for (int idx = tid; idx < 4096; idx += 256) {
            int r = idx >> 6, c = idx & 63;
            Wt[(size_t)(n0 + r) * K + k0 + c] = T[r][c];
        }
    } else {
        float pr = expf(logf((L_ + 1) / 2.0f) / (NPOS_ / 2));
        for (int idx = tid; idx < 4095; idx += 256) {
            int d = idx - 2047;
            int ad = d < 0 ? -d : d;
            int c = 0;
            for (int m = 1; m <= NPOS_ / 2; ++m) {
                float cw = powf(pr, (float)m);
                if (cw < (float)ad) c++;
            }
            sidx[idx] = (unsigned char)(d > 0 ? c : (d < 0 ? 17 + c : 34));
        }
        {
            int h = tid >> 5, n = tid & 31;
            float av = 0.f, au = 0.f;
            for (int d = 0; d < DK_; ++d) {
                float wp = wpos[(h * DK_ + d) * NPOS_ + n];
                av += vparam[h * DK_ + d] * wp;
                au += uparam[h * DK_ + d] * wp;
            }
            vw[tid] = av;
            uw[tid] = au;
        }
        __syncthreads();
        if (tid < H_ * 17) {
            int h = tid / 17, m = tid % 17;
            float su = 0.f, ss = 0.f;
            for (int t2 = m; t2 < 16; ++t2) {
                su += vw[h * NPOS_ + t2] - uw[h * NPOS_ + t2];
                ss += vw[h * NPOS_ + 16 + t2] - uw[h * NPOS_ + 16 + t2];
            }
            VU[h * 17 + m] = su * 0.125f;
            VS[h * 17 + m] = ss * 0.125f;
        }
    }
}

// ---------------------------------------------------------------------------
// RMSNorm (row of 768), fp32 in, bf16 out
// ---------------------------------------------------------------------------
__global__ __launch_bounds__(256) void rmsnorm_kernel(
    const float* __restrict__ x, const float* __restrict__ wgt, short* __restrict__ out)
{
    int row = blockIdx.x, tid = threadIdx.x;
    __shared__ float red[4];
    const float* xr = x + (size_t)row * D_;
    float ss = 0.f;
    for (int c = tid; c < D_; c += 256) { float f = xr[c]; ss += f * f; }
    for (int msk = 1; msk < 64; msk <<= 1) ss += __shfl_xor(ss, msk);
    if ((tid & 63) == 0) red[tid >> 6] = ss;
    __syncthreads();
    float tot = red[0] + red[1] + red[2] + red[3];
    float sc = rsqrtf(tot * (1.f / D_) + 1e-5f);
    for (int c = tid; c < D_; c += 256)
        out[(size_t)row * D_ + c] = f2bs(xr[c] * sc * wgt[c]);
}

// ---------------------------------------------------------------------------
// 64x64-tile bf16 MFMA GEMM with register-prefetched staging (wo, FFN2)
// ---------------------------------------------------------------------------
__global__ __launch_bounds__(256) void gemm64(
    const short* __restrict__ A, const short* __restrict__ Bt,
    const float* __restrict__ bias, const float* __restrict__ resid,
    void* __restrict__ outp,
    int M, int N, int K, int act, int out_f32)
{
    __shared__ __align__(16) short Al[64 * 72];
    __shared__ __align__(16) short Bl[64 * 72];
    int tid = threadIdx.x;
    int w = tid >> 6, lane = tid & 63, quad = lane >> 4, t = lane & 15;
    int m0b = blockIdx.y << 6, n0b = blockIdx.x << 6;
    int wr = (w >> 1) << 5, wc = (w & 1) << 5;
    int r0 = tid >> 3, c8 = (tid & 7) << 3;   // staging: rows r0, r0+32
    f32x4 acc[2][2] = {};
    bf16x8 pA[2], pB[2];
#pragma unroll
    for (int it = 0; it < 2; ++it) {
        pA[it] = *(const bf16x8*)&A[(size_t)(m0b + r0 + (it << 5)) * K + c8];
        pB[it] = *(const bf16x8*)&Bt[(size_t)(n0b + r0 + (it << 5)) * K + c8];
    }
    for (int kb = 0; kb < K; kb += 64) {
        __syncthreads();
#pragma unroll
        for (int it = 0; it < 2; ++it) {
            *(bf16x8*)&Al[(r0 + (it << 5)) * 72 + c8] = pA[it];
            *(bf16x8*)&Bl[(r0 + (it << 5)) * 72 + c8] = pB[it];
        }
        if (kb + 64 < K) {
#pragma unroll
            for (int it = 0; it < 2; ++it) {
                pA[it] = *(const bf16x8*)&A[(size_t)(m0b + r0 + (it << 5)) * K + kb + 64 + c8];
                pB[it] = *(const bf16x8*)&Bt[(size_t)(n0b + r0 + (it << 5)) * K + kb + 64 + c8];
            }
        }
        __syncthreads();
#pragma unroll
        for (int ks = 0; ks < 2; ++ks) {
            bf16x8 af0 = *(bf16x8*)&Al[(wr + t) * 72 + (ks << 5) + (quad << 3)];
            bf16x8 af1 = *(bf16x8*)&Al[(wr + 16 + t) * 72 + (ks << 5) + (quad << 3)];
            bf16x8 bf0 = *(bf16x8*)&Bl[(wc + t) * 72 + (ks << 5) + (quad << 3)];
            bf16x8 bf1 = *(bf16x8*)&Bl[(wc + 16 + t) * 72 + (ks << 5) + (quad << 3)];
            acc[0][0] = __builtin_amdgcn_mfma_f32_16x16x32_bf16(af0, bf0, acc[0][0], 0, 0, 0);
            acc[0][1] = __builtin_amdgcn_mfma_f32_16x16x32_bf16(af0, bf1, acc[0][1], 0, 0, 0);
            acc[1][0] = __builtin_amdgcn_mfma_f32_16x16x32_bf16(af1, bf0, acc[1][0], 0, 0, 0);
            acc[1][1] = __builtin_amdgcn_mfma_f32_16x16x32_bf16(af1, bf1, acc[1][1], 0, 0, 0);
        }
    }
#pragma unroll
    for (int ms = 0; ms < 2; ++ms)
#pragma unroll
        for (int ns = 0; ns < 2; ++ns)
#pragma unroll
            for (int r = 0; r < 4; ++r) {
                int row = m0b + wr + (ms << 4) + (quad << 2) + r;
                int col = n0b + wc + (ns << 4) + t;
                float v2 = acc[ms][ns][r];
                if (bias) v2 += bias[col];
                if (act == 1) v2 = 0.5f * v2 * (1.f + erff(v2 * 0.70710678118654752f));
                if (resid) v2 += resid[(size_t)row * N + col];
                if (out_f32) ((float*)outp)[(size_t)row * N + col] = v2;
                else ((short*)outp)[(size_t)row * N + col] = f2bs(v2);
            }
}

// ---------------------------------------------------------------------------
// 128x128-tile bf16 MFMA GEMM with register-prefetched staging (QKV, FFN1).
// uadd: if non-null, cols<512 get v = 0.125*(acc + uadd[col]).
// ---------------------------------------------------------------------------
__global__ __launch_bounds__(256) void gemm128(
    const short* __restrict__ A, const short* __restrict__ Bt,
    const float* __restrict__ bias, const float* __restrict__ uadd,
    void* __restrict__ outp, int M, int N, int K, int act)
{
    __shared__ __align__(16) short Al[128 * 72];
    __shared__ __align__(16) short Bl[128 * 72];
    int tid = threadIdx.x;
    int w = tid >> 6, lane = tid & 63, quad = lane >> 4, t = lane & 15;
    int m0b = blockIdx.y << 7, n0b = blockIdx.x << 7;
    int wm = (w >> 1) << 6, wn = (w & 1) << 6;
    int r0 = tid >> 3, c8 = (tid & 7) << 3;   // staging: rows r0 + 32*it
    f32x4 acc[4][4] = {};
    bf16x8 pA[4], pB[4];
#pragma unroll
    for (int it = 0; it < 4; ++it) {
        pA[it] = *(const bf16x8*)&A[(size_t)(m0b + r0 + (it << 5)) * K + c8];
        pB[it] = *(const bf16x8*)&Bt[(size_t)(n0b + r0 + (it << 5)) * K + c8];
    }
    for (int kb = 0; kb < K; kb += 64) {
        __syncthreads();
#pragma unroll
        for (int it = 0; it < 4; ++it) {
            *(bf16x8*)&Al[(r0 + (it << 5)) * 72 + c8] = pA[it];
            *(bf16x8*)&Bl[(r0 + (it << 5)) * 72 + c8] = pB[it];
        }
        if (kb + 64 < K) {
#pragma unroll
            for (int it = 0; it < 4; ++it) {
                pA[it] = *(const bf16x8*)&A[(size_t)(m0b + r0 + (it << 5)) * K + kb + 64 + c8];
                pB[it] = *(const bf16x8*)&Bt[(size_t)(n0b + r0 + (it << 5)) * K + kb + 64 + c8];
            }
        }
        __syncthreads();
#pragma unroll
        for (int ks = 0; ks < 2; ++ks) {
            bf16x8 af[4], bf[4];
#pragma unroll
            for (int ms = 0; ms < 4; ++ms)
                af[ms] = *(bf16x8*)&Al[(wm + ms * 16 + t) * 72 + (ks << 5) + (quad << 3)];
#pragma unroll
            for (int ns = 0; ns < 4; ++ns)
                bf[ns] = *(bf16x8*)&Bl[(wn + ns * 16 + t) * 72 + (ks << 5) + (quad << 3)];
#pragma unroll
            for (int ms = 0; ms < 4; ++ms)
#pragma unroll
                for (int ns = 0; ns < 4; ++ns)
                    acc[ms][ns] = __builtin_amdgcn_mfma_f32_16x16x32_bf16(af[ms], bf[ns], acc[ms][ns], 0, 0, 0);
        }
    }
#pragma unroll
    for (int ms = 0; ms < 4; ++ms)
#pragma unroll
        for (int ns = 0; ns < 4; ++ns)
#pragma unroll
            for (int r = 0; r < 4; ++r) {
                int row = m0b + wm + ms * 16 + (quad << 2) + r;
                int col = n0b + wn + ns * 16 + t;
                float v2 = acc[ms][ns][r];
                if (uadd && col < 512) v2 = 0.125f * (v2 + uadd[col]);
                if (bias) v2 += bias[col];
                if (act == 1) v2 = 0.5f * v2 * (1.f + erff(v2 * 0.70710678118654752f));
                ((short*)outp)[(size_t)row * N + col] = f2bs(v2);
            }
}

// ---------------------------------------------------------------------------
// qsuf v2: 256 blocks x 16 rows; wpos staged once per block in LDS (64 KB).
// Emits folded bias table Tg[row][h][35].
// ---------------------------------------------------------------------------
__global__ __launch_bounds__(256) void qsuf_kernel(
    const short* __restrict__ qkv, const float* __restrict__ wpos,
    const float* __restrict__ VU, const float* __restrict__ VS,
    float* __restrict__ Tg)
{
    __shared__ float wl[512 * 32];   // 64 KB
    __shared__ float qrow[512];
    __shared__ float qw[256];
    __shared__ float sU[136], sS[136];
    int tid = threadIdx.x;
    for (int idx = tid; idx < 4096; idx += 256)
        ((float4*)wl)[idx] = ((const float4*)wpos)[idx];
    int r0 = blockIdx.x << 4;
    int h = tid >> 5, n = tid & 31;
    for (int rr = 0; rr < 16; ++rr) {
        int row = r0 + rr;
        __syncthreads();   // wl ready (rr=0) / previous row fully consumed
        const short* base = qkv + (size_t)row * 1792;
        qrow[tid]       = bs2f(base[tid]);
        qrow[tid + 256] = bs2f(base[tid + 256]);
        __syncthreads();
        float acc = 0.f;
        for (int d = 0; d < DK_; ++d)
            acc += qrow[h * DK_ + d] * wl[(h * DK_ + d) * 32 + n];
        qw[tid] = acc;
        __syncthreads();
        if (tid < 136) {
            int hh = tid / 17, m = tid % 17;
            float su = 0.f, ss = 0.f;
            for (int t2 = m; t2 < 16; ++t2) { su += qw[hh * NPOS_ + t2]; ss += qw[hh * NPOS_ + 16 + t2]; }
            sU[tid] = su + VU[tid];
            sS[tid] = ss + VS[tid];
        }
        __syncthreads();
        if (tid < 280) {
            int h2 = tid / 35, s = tid % 35;
            int m = s < 17 ? s : (s < 34 ? s - 17 : 0);
            float su = sU[h2 * 17 + m], ss = sS[h2 * 17 + m];
            Tg[(size_t)row * 280 + tid] = s < 17 ? su + ss : (s < 34 ? su - ss : su);
        }
    }
}

// ---------------------------------------------------------------------------
// vtrans: V section of qkv -> vT[bh][dv][j]  (per-head transposed V)
// ---------------------------------------------------------------------------
__global__ __launch_bounds__(256) void vtrans_kernel(
    const short* __restrict__ qkv, short* __restrict__ vT)
{
    __shared__ __align__(16) short T[64 * 104];
    int tid = threadIdx.x;
    int bh = blockIdx.y, b = bh >> 3, h = bh & 7;
    int j0 = blockIdx.x << 6;
#pragma unroll
    for (int it = 0; it < 3; ++it) {
        int idx = tid + (it << 8);
        int row = idx / 12, c8 = (idx % 12) << 3;
        *(bf16x8*)&T[row * 104 + c8] =
            *(const bf16x8*)&qkv[(size_t)(b * L_ + j0 + row) * 1792 + 1024 + h * DV_ + c8];
    }
    __syncthreads();
#pragma unroll
    for (int it = 0; it < 3; ++it) {
        int dv = (tid & 31) + (it << 5);
        int j8 = ((tid >> 5) & 7) << 3;
        bf16x8 o;
#pragma unroll
        for (int e = 0; e < 8; ++e) o[e] = __builtin_bit_cast(__bf16, T[(j8 + e) * 104 + dv]);
        *(bf16x8*)&vT[((size_t)bh * DV_ + dv) * L_ + j0 + j8] = o;
    }
}

// ---------------------------------------------------------------------------
// Flash attention (round-10 structure, unchanged): 128-j tiles, register
// prefetch, vT-staged V, padded strides 140, LDS bias tables.
// Grid: (L/64 = 32, B*H = 16), 4 waves/block.
// ---------------------------------------------------------------------------
__global__ __launch_bounds__(256) void flash_kernel(
    const short* __restrict__ qkv, const short* __restrict__ vT,
    const float* __restrict__ Tg, const unsigned char* __restrict__ sidx_g,
    short* __restrict__ ao)
{
    __shared__ __align__(16) short Kl[128 * 72];   // [j][d]
    __shared__ __align__(16) short Vt[96 * 140];   // [dv][j]
    __shared__ __align__(16) short Pl[64 * 140];   // [il][j]
    __shared__ float Tt[64 * 36];
    __shared__ unsigned char sidxl[4096];
    int tid = threadIdx.x, w = tid >> 6, lane = tid & 63, quad = lane >> 4, t = lane & 15;
    int bh = blockIdx.y, b = bh >> 3, h = bh & 7;
    int i0 = blockIdx.x << 6;

    for (int idx = tid; idx < 64 * 35; idx += 256) {
        int il = idx / 35, s = idx % 35;
        Tt[il * 36 + s] = Tg[(size_t)(b * L_ + i0 + il) * 280 + h * 35 + s];
    }
    for (int idx = tid; idx < 4095; idx += 256) sidxl[idx] = sidx_g[idx];

    int iq = i0 + w * 16 + t;
    const short* qbase = qkv + (size_t)(b * L_ + iq) * 1792 + h * DK_;
    bf16x8 qf0 = *(const bf16x8*)(qbase + (quad << 3));
    bf16x8 qf1 = *(const bf16x8*)(qbase + 32 + (quad << 3));

    f32x4 O[6] = {};
    float lsum[4] = {0.f, 0.f, 0.f, 0.f};

    int kr = tid >> 3, kc = (tid & 7) << 3;
    int vdv = tid >> 4, vj8 = (tid & 15) << 3;
    bf16x8 kpre[4], vpre[6];
    {
        const short* kb0 = &qkv[(size_t)(b * L_ + kr) * 1792 + 512 + h * DK_ + kc];
#pragma unroll
        for (int it = 0; it < 4; ++it)
            kpre[it] = *(const bf16x8*)(kb0 + (size_t)(it << 5) * 1792);
        const short* vb0 = &vT[(size_t)bh * DV_ * L_];
#pragma unroll
        for (int it = 0; it < 6; ++it)
            vpre[it] = *(const bf16x8*)(vb0 + (size_t)(vdv + (it << 4)) * L_ + vj8);
    }

    for (int j0 = 0; j0 < L_; j0 += 128) {
        __syncthreads();
#pragma unroll
        for (int it = 0; it < 4; ++it)
            *(bf16x8*)&Kl[(kr + (it << 5)) * 72 + kc] = kpre[it];
#pragma unroll
        for (int it = 0; it < 6; ++it)
            *(bf16x8*)&Vt[(vdv + (it << 4)) * 140 + vj8] = vpre[it];
        {
            int jn = (j0 + 128 < L_) ? j0 + 128 : 0;
            const short* kb0 = &qkv[(size_t)(b * L_ + jn + kr) * 1792 + 512 + h * DK_ + kc];
#pragma unroll
            for (int it = 0; it < 4; ++it)
                kpre[it] = *(const bf16x8*)(kb0 + (size_t)(it << 5) * 1792);
            const short* vb0 = &vT[(size_t)bh * DV_ * L_ + jn];
#pragma unroll
            for (int it = 0; it < 6; ++it)
                vpre[it] = *(const bf16x8*)(vb0 + (size_t)(vdv + (it << 4)) * L_ + vj8);
        }
        __syncthreads();

        f32x4 S[8];
#pragma unroll
        for (int ct = 0; ct < 8; ++ct) {
            bf16x8 b0 = *(bf16x8*)&Kl[(ct * 16 + t) * 72 + (quad << 3)];
            bf16x8 b1 = *(bf16x8*)&Kl[(ct * 16 + t) * 72 + 32 + (quad << 3)];
            f32x4 z = {};
            z = __builtin_amdgcn_mfma_f32_16x16x32_bf16(qf0, b0, z, 0, 0, 0);
            S[ct] = __builtin_amdgcn_mfma_f32_16x16x32_bf16(qf1, b1, z, 0, 0, 0);
        }
#pragma unroll
        for (int r = 0; r < 4; ++r) {
            int il = w * 16 + (quad << 2) + r;
            int i = i0 + il;
            const float* Trow = &Tt[il * 36];
#pragma unroll
            for (int ct = 0; ct < 8; ++ct) {
                int j = j0 + ct * 16 + t;
                int s = sidxl[j - i + 2047];
                float p = __expf(S[ct][r] + Trow[s]);
                short pb = f2bs(p);
                lsum[r] += bs2f(pb);
                Pl[il * 140 + ct * 16 + t] = pb;
            }
        }
#pragma unroll
        for (int ks = 0; ks < 4; ++ks) {
            bf16x8 pa = *(bf16x8*)&Pl[(w * 16 + t) * 140 + (ks << 5) + (quad << 3)];
#pragma unroll
            for (int dv = 0; dv < 6; ++dv) {
                bf16x8 vb = *(bf16x8*)&Vt[(dv * 16 + t) * 140 + (ks << 5) + (quad << 3)];
                O[dv] = __builtin_amdgcn_mfma_f32_16x16x32_bf16(pa, vb, O[dv], 0, 0, 0);
            }
        }
    }
#pragma unroll
    for (int r = 0; r < 4; ++r) {
        float lr = lsum[r];
        lr += __shfl_xor(lr, 1);
        lr += __shfl_xor(lr, 2);
        lr += __shfl_xor(lr, 4);
        lr += __shfl_xor(lr, 8);
        float inv = 1.f / lr;
        int i = i0 + w * 16 + (quad << 2) + r;
        size_t base = (size_t)(b * L_ + i) * D_ + h * DV_;
#pragma unroll
        for (int dv = 0; dv < 6; ++dv) ao[base + dv * 16 + t] = f2bs(O[dv][r] * inv);
    }
}

// ---------------------------------------------------------------------------
extern "C" void kernel_launch(void* const* d_in, const int* in_sizes, int n_in,
                              void* d_out, int out_size, void* d_ws, size_t ws_size,
                              hipStream_t stream)
{
    const float* x    = (const float*)d_in[0];
    const float* n1w  = (const float*)d_in[1];
    const float* n2w  = (const float*)d_in[2];
    const float* wq   = (const float*)d_in[3];
    const float* wk   = (const float*)d_in[4];
    const float* wv   = (const float*)d_in[5];
    const float* wo   = (const float*)d_in[6];
    const float* bo   = (const float*)d_in[7];
    const float* up   = (const float*)d_in[8];
    const float* vp   = (const float*)d_in[9];
    const float* wpos = (const float*)d_in[10];
    const float* w1   = (const float*)d_in[11];
    const float* b1   = (const float*)d_in[12];
    const float* w2   = (const float*)d_in[13];
    const float* b2   = (const float*)d_in[14];

    char* ws = (char*)d_ws;
    short* h1   = (short*)(ws + 0);         // [4096,768] bf16
    short* qkv  = (short*)(ws + 6291456);   // [4096,1792] bf16, ends 20971520
    float* Tg   = (float*)(ws + 20971520);  // [4096,8,35] f32, ends 25559040
    float* VUg  = (float*)(ws + 25559040);
    float* VSg  = (float*)(ws + 25560064);
    unsigned char* sidx = (unsigned char*)(ws + 25561088);  // [4096]
    short* ao   = (short*)(ws + 25569280);  // [4096,768] bf16
    float* x2   = (float*)(ws + 31860736);  // [4096,768] f32, ends 44443648
    short* vT   = (short*)(ws + 31860736);  // [16,96,2048] bf16 overlays x2 (dead before wo-gemm)
    short* wqkvT= (short*)(ws + 44443648);  // [1792,768] bf16, ends 47196160
    short* woT  = (short*)(ws + 47196160);  // [768,768]
    short* w1T  = (short*)(ws + 48375808);  // [1536,768]
    short* w2T  = (short*)(ws + 50735104);  // [768,1536], ends 53094400
    short* f1   = (short*)(ws + 0);         // [4096,1536] overlays h1+qkv head (dead)
    short* h2n  = (short*)(ws + 14680064);  // [4096,768] overlays qkv tail (dead)

    prep_kernel<<<1057, 256, 0, stream>>>(wq, wk, wv, wo, w1, w2, vp, up, wpos,
                                          wqkvT, woT, w1T, w2T, sidx, VUg, VSg);
    rmsnorm_kernel<<<4096, 256, 0, stream>>>(x, n1w, h1);
    gemm128<<<dim3(14, 32), 256, 0, stream>>>(h1, wqkvT, nullptr, up, qkv, 4096, 1792, 768, 0);
    qsuf_kernel<<<256, 256, 0, stream>>>(qkv, wpos, VUg, VSg, Tg);
    vtrans_kernel<<<dim3(32, 16), 256, 0, stream>>>(qkv, vT);
    flash_kernel<<<dim3(32, 16), 256, 0, stream>>>(qkv, vT, Tg, sidx, ao);
    gemm64<<<dim3(12, 64), 256, 0, stream>>>(ao, woT, bo, x, x2, 4096, 768, 768, 0, 1);
    rmsnorm_kernel<<<4096, 256, 0, stream>>>(x2, n2w, h2n);
    gemm128<<<dim3(12, 32), 256, 0, stream>>>(h2n, w1T, b1, nullptr, f1, 4096, 1536, 768, 1);
    gemm64<<<dim3(12, 64), 256, 0, stream>>>(f1, w2T, b2, x2, d_out, 4096, 768, 1536, 0, 1);
}

// Round 12
// 336.004 us; speedup vs baseline: 1.2608x; 1.0293x over previous
//
#include <hip/hip_runtime.h>

#define B_ 2
#define L_ 2048
#define D_ 768
#define H_ 8
#define DK_ 64
#define DV_ 96
#define NPOS_ 32

typedef __attribute__((ext_vector_type(8))) __bf16 bf16x8;
typedef __attribute__((ext_vector_type(4))) float f32x4;

static __device__ __forceinline__ float bs2f(short s) {
    return (float)__builtin_bit_cast(__bf16, s);
}
static __device__ __forceinline__ short f2bs(float f) {
    return __builtin_bit_cast(short, (__bf16)f);
}

// ---------------------------------------------------------------------------
// prep (fused with rmsnorm1): blocks 0..1055 transpose weights; block 1056
// builds sidx + VU/VS tables; blocks 1057.. do rmsnorm rows of x -> h1.
// ---------------------------------------------------------------------------
__global__ __launch_bounds__(256) void prep_kernel(
    const float* __restrict__ wq, const float* __restrict__ wk,
    const float* __restrict__ wv, const float* __restrict__ wo,
    const float* __restrict__ w1, const float* __restrict__ w2,
    const float* __restrict__ vparam, const float* __restrict__ uparam,
    const float* __restrict__ wpos,
    short* __restrict__ wqkvT, short* __restrict__ woT,
    short* __restrict__ w1T, short* __restrict__ w2T,
    unsigned char* __restrict__ sidx, float* __restrict__ VU, float* __restrict__ VS,
    const float* __restrict__ x, const float* __restrict__ n1w, short* __restrict__ h1)
{
    __shared__ short T[64][66];
    __shared__ float vw[H_ * NPOS_];
    __shared__ float uw[H_ * NPOS_];
    __shared__ float red[4];
    int blk = blockIdx.x, tid = threadIdx.x;
    if (blk < 1056) {
        const float* W; short* Wt; int K, N, bx, by;
        if (blk < 96)       { W = wq; Wt = wqkvT;              K = 768;  N = 512;  int b = blk;       bx = b % 8;  by = b / 8; }
        else if (blk < 192) { W = wk; Wt = wqkvT + 512 * 768;  K = 768;  N = 512;  int b = blk - 96;  bx = b % 8;  by = b / 8; }
        else if (blk < 336) { W = wv; Wt = wqkvT + 1024 * 768; K = 768;  N = 768;  int b = blk - 192; bx = b % 12; by = b / 12; }
        else if (blk < 480) { W = wo; Wt = woT;                K = 768;  N = 768;  int b = blk - 336; bx = b % 12; by = b / 12; }
        else if (blk < 768) { W = w1; Wt = w1T;                K = 768;  N = 1536; int b = blk - 480; bx = b % 24; by = b / 24; }
        else                { W = w2; Wt = w2T;                K = 1536; N = 768;  int b = blk - 768; bx = b % 12; by = b / 12; }
        int n0 = bx << 6, k0 = by << 6;
        for (int idx = tid; idx < 4096; idx += 256) {
            int r = idx >> 6, c = idx & 63;
            T[c][r] = f2bs(W[(size_t)(k0 + r) * N + n0 + c]);
        }
        __syncthreads();
        for (int idx = tid; idx < 4096; idx += 256) {
            int r = idx >> 6, c = idx & 63;
            Wt[(size_t)(n0 + r) * K + k0 + c] = T[r][c];
        }
    } else if (blk == 1056) {
        float pr = expf(logf((L_ + 1) / 2.0f) / (NPOS_ / 2));
        for (int idx = tid; idx < 4095; idx += 256) {
            int d = idx - 2047;
            int ad = d < 0 ? -d : d;
            int c = 0;
            for (int m = 1; m <= NPOS_ / 2; ++m) {
                float cw = powf(pr, (float)m);
                if (cw < (float)ad) c++;
            }
            sidx[idx] = (unsigned char)(d > 0 ? c : (d < 0 ? 17 + c : 34));
        }
        {
            int h = tid >> 5, n = tid & 31;
            float av = 0.f, au = 0.f;
            for (int d = 0; d < DK_; ++d) {
                float wp = wpos[(h * DK_ + d) * NPOS_ + n];
                av += vparam[h * DK_ + d] * wp;
                au += uparam[h * DK_ + d] * wp;
            }
            vw[tid] = av;
            uw[tid] = au;
        }
        __syncthreads();
        if (tid < H_ * 17) {
            int h = tid / 17, m = tid % 17;
            float su = 0.f, ss = 0.f;
            for (int t2 = m; t2 < 16; ++t2) {
                su += vw[h * NPOS_ + t2] - uw[h * NPOS_ + t2];
                ss += vw[h * NPOS_ + 16 + t2] - uw[h * NPOS_ + 16 + t2];
            }
            VU[h * 17 + m] = su * 0.125f;
            VS[h * 17 + m] = ss * 0.125f;
        }
    } else {
        int row = blk - 1057;
        const float* xr = x + (size_t)row * D_;
        float ss = 0.f;
        for (int c = tid; c < D_; c += 256) { float f = xr[c]; ss += f * f; }
        for (int msk = 1; msk < 64; msk <<= 1) ss += __shfl_xor(ss, msk);
        if ((tid & 63) == 0) red[tid >> 6] = ss;
        __syncthreads();
        float tot = red[0] + red[1] + red[2] + red[3];
        float sc = rsqrtf(tot * (1.f / D_) + 1e-5f);
        for (int c = tid; c < D_; c += 256)
            h1[(size_t)row * D_ + c] = f2bs(xr[c] * sc * n1w[c]);
    }
}

// ---------------------------------------------------------------------------
// RMSNorm (row of 768), fp32 in, bf16 out (second norm only)
// ---------------------------------------------------------------------------
__global__ __launch_bounds__(256) void rmsnorm_kernel(
    const float* __restrict__ x, const float* __restrict__ wgt, short* __restrict__ out)
{
    int row = blockIdx.x, tid = threadIdx.x;
    __shared__ float red[4];
    const float* xr = x + (size_t)row * D_;
    float ss = 0.f;
    for (int c = tid; c < D_; c += 256) { float f = xr[c]; ss += f * f; }
    for (int msk = 1; msk < 64; msk <<= 1) ss += __shfl_xor(ss, msk);
    if ((tid & 63) == 0) red[tid >> 6] = ss;
    __syncthreads();
    float tot = red[0] + red[1] + red[2] + red[3];
    float sc = rsqrtf(tot * (1.f / D_) + 1e-5f);
    for (int c = tid; c < D_; c += 256)
        out[(size_t)row * D_ + c] = f2bs(xr[c] * sc * wgt[c]);
}

// ---------------------------------------------------------------------------
// 64x64-tile bf16 MFMA GEMM, BK=128 (halved barrier count), register
// prefetch. For wo and FFN2 (K multiple of 128).
// ---------------------------------------------------------------------------
__global__ __launch_bounds__(256) void gemm64(
    const short* __restrict__ A, const short* __restrict__ Bt,
    const float* __restrict__ bias, const float* __restrict__ resid,
    void* __restrict__ outp,
    int M, int N, int K, int act, int out_f32)
{
    __shared__ __align__(16) short Al[64 * 136];
    __shared__ __align__(16) short Bl[64 * 136];
    int tid = threadIdx.x;
    int w = tid >> 6, lane = tid & 63, quad = lane >> 4, t = lane & 15;
    int m0b = blockIdx.y << 6, n0b = blockIdx.x << 6;
    int wr = (w >> 1) << 5, wc = (w & 1) << 5;
    int rA = tid >> 4, c8 = (tid & 15) << 3;   // rows rA+16*it, cols c8..c8+7
    f32x4 acc[2][2] = {};
    bf16x8 pA[4], pB[4];
#pragma unroll
    for (int it = 0; it < 4; ++it) {
        pA[it] = *(const bf16x8*)&A[(size_t)(m0b + rA + (it << 4)) * K + c8];
        pB[it] = *(const bf16x8*)&Bt[(size_t)(n0b + rA + (it << 4)) * K + c8];
    }
    for (int kb = 0; kb < K; kb += 128) {
        __syncthreads();
#pragma unroll
        for (int it = 0; it < 4; ++it) {
            *(bf16x8*)&Al[(rA + (it << 4)) * 136 + c8] = pA[it];
            *(bf16x8*)&Bl[(rA + (it << 4)) * 136 + c8] = pB[it];
        }
        if (kb + 128 < K) {
#pragma unroll
            for (int it = 0; it < 4; ++it) {
                pA[it] = *(const bf16x8*)&A[(size_t)(m0b + rA + (it << 4)) * K + kb + 128 + c8];
                pB[it] = *(const bf16x8*)&Bt[(size_t)(n0b + rA + (it << 4)) * K + kb + 128 + c8];
            }
        }
        __syncthreads();
#pragma unroll
        for (int ks = 0; ks < 4; ++ks) {
            bf16x8 af0 = *(bf16x8*)&Al[(wr + t) * 136 + (ks << 5) + (quad << 3)];
            bf16x8 af1 = *(bf16x8*)&Al[(wr + 16 + t) * 136 + (ks << 5) + (quad << 3)];
            bf16x8 bf0 = *(bf16x8*)&Bl[(wc + t) * 136 + (ks << 5) + (quad << 3)];
            bf16x8 bf1 = *(bf16x8*)&Bl[(wc + 16 + t) * 136 + (ks << 5) + (quad << 3)];
            acc[0][0] = __builtin_amdgcn_mfma_f32_16x16x32_bf16(af0, bf0, acc[0][0], 0, 0, 0);
            acc[0][1] = __builtin_amdgcn_mfma_f32_16x16x32_bf16(af0, bf1, acc[0][1], 0, 0, 0);
            acc[1][0] = __builtin_amdgcn_mfma_f32_16x16x32_bf16(af1, bf0, acc[1][0], 0, 0, 0);
            acc[1][1] = __builtin_amdgcn_mfma_f32_16x16x32_bf16(af1, bf1, acc[1][1], 0, 0, 0);
        }
    }
#pragma unroll
    for (int ms = 0; ms < 2; ++ms)
#pragma unroll
        for (int ns = 0; ns < 2; ++ns)
#pragma unroll
            for (int r = 0; r < 4; ++r) {
                int row = m0b + wr + (ms << 4) + (quad << 2) + r;
                int col = n0b + wc + (ns << 4) + t;
                float v2 = acc[ms][ns][r];
                if (bias) v2 += bias[col];
                if (act == 1) v2 = 0.5f * v2 * (1.f + erff(v2 * 0.70710678118654752f));
                if (resid) v2 += resid[(size_t)row * N + col];
                if (out_f32) ((float*)outp)[(size_t)row * N + col] = v2;
                else ((short*)outp)[(size_t)row * N + col] = f2bs(v2);
            }
}

// ---------------------------------------------------------------------------
// 128x128-tile bf16 MFMA GEMM with register-prefetched staging (QKV, FFN1).
// uadd: if non-null, cols<512 get v = 0.125*(acc + uadd[col]).
// ---------------------------------------------------------------------------
__global__ __launch_bounds__(256) void gemm128(
    const short* __restrict__ A, const short* __restrict__ Bt,
    const float* __restrict__ bias, const float* __restrict__ uadd,
    void* __restrict__ outp, int M, int N, int K, int act)
{
    __shared__ __align__(16) short Al[128 * 72];
    __shared__ __align__(16) short Bl[128 * 72];
    int tid = threadIdx.x;
    int w = tid >> 6, lane = tid & 63, quad = lane >> 4, t = lane & 15;
    int m0b = blockIdx.y << 7, n0b = blockIdx.x << 7;
    int wm = (w >> 1) << 6, wn = (w & 1) << 6;
    int r0 = tid >> 3, c8 = (tid & 7) << 3;
    f32x4 acc[4][4] = {};
    bf16x8 pA[4], pB[4];
#pragma unroll
    for (int it = 0; it < 4; ++it) {
        pA[it] = *(const bf16x8*)&A[(size_t)(m0b + r0 + (it << 5)) * K + c8];
        pB[it] = *(const bf16x8*)&Bt[(size_t)(n0b + r0 + (it << 5)) * K + c8];
    }
    for (int kb = 0; kb < K; kb += 64) {
        __syncthreads();
#pragma unroll
        for (int it = 0; it < 4; ++it) {
            *(bf16x8*)&Al[(r0 + (it << 5)) * 72 + c8] = pA[it];
            *(bf16x8*)&Bl[(r0 + (it << 5)) * 72 + c8] = pB[it];
        }
        if (kb + 64 < K) {
#pragma unroll
            for (int it = 0; it < 4; ++it) {
                pA[it] = *(const bf16x8*)&A[(size_t)(m0b + r0 + (it << 5)) * K + kb + 64 + c8];
                pB[it] = *(const bf16x8*)&Bt[(size_t)(n0b + r0 + (it << 5)) * K + kb + 64 + c8];
            }
        }
        __syncthreads();
#pragma unroll
        for (int ks = 0; ks < 2; ++ks) {
            bf16x8 af[4], bf[4];
#pragma unroll
            for (int ms = 0; ms < 4; ++ms)
                af[ms] = *(bf16x8*)&Al[(wm + ms * 16 + t) * 72 + (ks << 5) + (quad << 3)];
#pragma unroll
            for (int ns = 0; ns < 4; ++ns)
                bf[ns] = *(bf16x8*)&Bl[(wn + ns * 16 + t) * 72 + (ks << 5) + (quad << 3)];
#pragma unroll
            for (int ms = 0; ms < 4; ++ms)
#pragma unroll
                for (int ns = 0; ns < 4; ++ns)
                    acc[ms][ns] = __builtin_amdgcn_mfma_f32_16x16x32_bf16(af[ms], bf[ns], acc[ms][ns], 0, 0, 0);
        }
    }
#pragma unroll
    for (int ms = 0; ms < 4; ++ms)
#pragma unroll
        for (int ns = 0; ns < 4; ++ns)
#pragma unroll
            for (int r = 0; r < 4; ++r) {
                int row = m0b + wm + ms * 16 + (quad << 2) + r;
                int col = n0b + wn + ns * 16 + t;
                float v2 = acc[ms][ns][r];
                if (uadd && col < 512) v2 = 0.125f * (v2 + uadd[col]);
                if (bias) v2 += bias[col];
                if (act == 1) v2 = 0.5f * v2 * (1.f + erff(v2 * 0.70710678118654752f));
                ((short*)outp)[(size_t)row * N + col] = f2bs(v2);
            }
}

// ---------------------------------------------------------------------------
// qv: fused qsuf (blocks 0..255, 16 rows each) + permuted vtrans (blocks
// 256..511, 128-j tiles). vT stores, within each 128-j tile, position
// p = t*8+ct  <-  V[j = ct*16 + t]  (matches flash's b128 P-write layout).
// ---------------------------------------------------------------------------
__global__ __launch_bounds__(256) void qv_kernel(
    const short* __restrict__ qkv, const float* __restrict__ wpos,
    const float* __restrict__ VU, const float* __restrict__ VS,
    float* __restrict__ Tg, short* __restrict__ vT)
{
    __shared__ __align__(16) char arena[69696];
    int blk = blockIdx.x, tid = threadIdx.x;
    if (blk < 256) {
        float* wl   = (float*)arena;            // 512*32
        float* qrow = (float*)(arena + 65536);  // 512
        float* qw   = (float*)(arena + 67584);  // 256
        float* sU   = (float*)(arena + 68608);  // 136
        float* sS   = (float*)(arena + 69152);  // 136
        for (int idx = tid; idx < 4096; idx += 256)
            ((float4*)wl)[idx] = ((const float4*)wpos)[idx];
        int r0 = blk << 4;
        int h = tid >> 5, n = tid & 31;
        for (int rr = 0; rr < 16; ++rr) {
            int row = r0 + rr;
            __syncthreads();
            const short* base = qkv + (size_t)row * 1792;
            qrow[tid]       = bs2f(base[tid]);
            qrow[tid + 256] = bs2f(base[tid + 256]);
            __syncthreads();
            float acc = 0.f;
            for (int d = 0; d < DK_; ++d)
                acc += qrow[h * DK_ + d] * wl[(h * DK_ + d) * 32 + n];
            qw[tid] = acc;
            __syncthreads();
            if (tid < 136) {
                int hh = tid / 17, m = tid % 17;
                float su = 0.f, ss = 0.f;
                for (int t2 = m; t2 < 16; ++t2) { su += qw[hh * NPOS_ + t2]; ss += qw[hh * NPOS_ + 16 + t2]; }
                sU[tid] = su + VU[tid];
                sS[tid] = ss + VS[tid];
            }
            __syncthreads();
            if (tid < 280) {
                int h2 = tid / 35, s = tid % 35;
                int m = s < 17 ? s : (s < 34 ? s - 17 : 0);
                float su = sU[h2 * 17 + m], ss = sS[h2 * 17 + m];
                Tg[(size_t)row * 280 + tid] = s < 17 ? su + ss : (s < 34 ? su - ss : su);
            }
        }
    } else {
        short* T = (short*)arena;   // [128][104]
        int vb = blk - 256;
        int bh = vb >> 4, b = bh >> 3, h = bh & 7;
        int j0 = (vb & 15) << 7;
#pragma unroll
        for (int it = 0; it < 6; ++it) {
            int idx = tid + (it << 8);
            int row = idx / 12, c8 = (idx % 12) << 3;
            *(bf16x8*)&T[row * 104 + c8] =
                *(const bf16x8*)&qkv[(size_t)(b * L_ + j0 + row) * 1792 + 1024 + h * DV_ + c8];
        }
        __syncthreads();
#pragma unroll
        for (int it = 0; it < 6; ++it) {
            int idx = tid + (it << 8);
            int dv = idx >> 4, t = idx & 15;
            bf16x8 o;
#pragma unroll
            for (int ct = 0; ct < 8; ++ct)
                o[ct] = __builtin_bit_cast(__bf16, T[(ct * 16 + t) * 104 + dv]);
            *(bf16x8*)&vT[((size_t)bh * DV_ + dv) * L_ + j0 + t * 8] = o;
        }
    }
}

// ---------------------------------------------------------------------------
// Flash attention: 128-j tiles, register prefetch, permuted-P b128 writes
// (Pl position p = t*8+ct, matching permuted vT), padded strides 140.
// Grid: (L/64 = 32, B*H = 16), 4 waves/block.
// ---------------------------------------------------------------------------
__global__ __launch_bounds__(256) void flash_kernel(
    const short* __restrict__ qkv, const short* __restrict__ vT,
    const float* __restrict__ Tg, const unsigned char* __restrict__ sidx_g,
    short* __restrict__ ao)
{
    __shared__ __align__(16) short Kl[128 * 72];   // [j][d]
    __shared__ __align__(16) short Vt[96 * 140];   // [dv][p]
    __shared__ __align__(16) short Pl[64 * 140];   // [il][p]
    __shared__ float Tt[64 * 36];
    __shared__ unsigned char sidxl[4096];
    int tid = threadIdx.x, w = tid >> 6, lane = tid & 63, quad = lane >> 4, t = lane & 15;
    int bh = blockIdx.y, b = bh >> 3, h = bh & 7;
    int i0 = blockIdx.x << 6;

    for (int idx = tid; idx < 64 * 35; idx += 256) {
        int il = idx / 35, s = idx % 35;
        Tt[il * 36 + s] = Tg[(size_t)(b * L_ + i0 + il) * 280 + h * 35 + s];
    }
    for (int idx = tid; idx < 4095; idx += 256) sidxl[idx] = sidx_g[idx];

    int iq = i0 + w * 16 + t;
    const short* qbase = qkv + (size_t)(b * L_ + iq) * 1792 + h * DK_;
    bf16x8 qf0 = *(const bf16x8*)(qbase + (quad << 3));
    bf16x8 qf1 = *(const bf16x8*)(qbase + 32 + (quad << 3));

    f32x4 O[6] = {};
    float lsum[4] = {0.f, 0.f, 0.f, 0.f};

    int kr = tid >> 3, kc = (tid & 7) << 3;
    int vdv = tid >> 4, vj8 = (tid & 15) << 3;
    bf16x8 kpre[4], vpre[6];
    {
        const short* kb0 = &qkv[(size_t)(b * L_ + kr) * 1792 + 512 + h * DK_ + kc];
#pragma unroll
        for (int it = 0; it < 4; ++it)
            kpre[it] = *(const bf16x8*)(kb0 + (size_t)(it << 5) * 1792);
        const short* vb0 = &vT[(size_t)bh * DV_ * L_];
#pragma unroll
        for (int it = 0; it < 6; ++it)
            vpre[it] = *(const bf16x8*)(vb0 + (size_t)(vdv + (it << 4)) * L_ + vj8);
    }

    for (int j0 = 0; j0 < L_; j0 += 128) {
        __syncthreads();
#pragma unroll
        for (int it = 0; it < 4; ++it)
            *(bf16x8*)&Kl[(kr + (it << 5)) * 72 + kc] = kpre[it];
#pragma unroll
        for (int it = 0; it < 6; ++it)
            *(bf16x8*)&Vt[(vdv + (it << 4)) * 140 + vj8] = vpre[it];
        {
            int jn = (j0 + 128 < L_) ? j0 + 128 : 0;
            const short* kb0 = &qkv[(size_t)(b * L_ + jn + kr) * 1792 + 512 + h * DK_ + kc];
#pragma unroll
            for (int it = 0; it < 4; ++it)
                kpre[it] = *(const bf16x8*)(kb0 + (size_t)(it << 5) * 1792);
            const short* vb0 = &vT[(size_t)bh * DV_ * L_ + jn];
#pragma unroll
            for (int it = 0; it < 6; ++it)
                vpre[it] = *(const bf16x8*)(vb0 + (size_t)(vdv + (it << 4)) * L_ + vj8);
        }
        __syncthreads();

        f32x4 S[8];
#pragma unroll
        for (int ct = 0; ct < 8; ++ct) {
            bf16x8 b0 = *(bf16x8*)&Kl[(ct * 16 + t) * 72 + (quad << 3)];
            bf16x8 b1 = *(bf16x8*)&Kl[(ct * 16 + t) * 72 + 32 + (quad << 3)];
            f32x4 z = {};
            z = __builtin_amdgcn_mfma_f32_16x16x32_bf16(qf0, b0, z, 0, 0, 0);
            S[ct] = __builtin_amdgcn_mfma_f32_16x16x32_bf16(qf1, b1, z, 0, 0, 0);
        }
#pragma unroll
        for (int r = 0; r < 4; ++r) {
            int il = w * 16 + (quad << 2) + r;
            int i = i0 + il;
            const float* Trow = &Tt[il * 36];
            bf16x8 pv8;
#pragma unroll
            for (int ct = 0; ct < 8; ++ct) {
                int j = j0 + ct * 16 + t;
                int s = sidxl[j - i + 2047];
                float p = __expf(S[ct][r] + Trow[s]);
                __bf16 pb = (__bf16)p;
                pv8[ct] = pb;
                lsum[r] += (float)pb;
            }
            *(bf16x8*)&Pl[il * 140 + t * 8] = pv8;   // positions p = t*8+ct
        }
#pragma unroll
        for (int ks = 0; ks < 4; ++ks) {
            bf16x8 pa = *(bf16x8*)&Pl[(w * 16 + t) * 140 + (ks << 5) + (quad << 3)];
#pragma unroll
            for (int dv = 0; dv < 6; ++dv) {
                bf16x8 vb = *(bf16x8*)&Vt[(dv * 16 + t) * 140 + (ks << 5) + (quad << 3)];
                O[dv] = __builtin_amdgcn_mfma_f32_16x16x32_bf16(pa, vb, O[dv], 0, 0, 0);
            }
        }
    }
#pragma unroll
    for (int r = 0; r < 4; ++r) {
        float lr = lsum[r];
        lr += __shfl_xor(lr, 1);
        lr += __shfl_xor(lr, 2);
        lr += __shfl_xor(lr, 4);
        lr += __shfl_xor(lr, 8);
        float inv = 1.f / lr;
        int i = i0 + w * 16 + (quad << 2) + r;
        size_t base = (size_t)(b * L_ + i) * D_ + h * DV_;
#pragma unroll
        for (int dv = 0; dv < 6; ++dv) ao[base + dv * 16 + t] = f2bs(O[dv][r] * inv);
    }
}

// ---------------------------------------------------------------------------
extern "C" void kernel_launch(void* const* d_in, const int* in_sizes, int n_in,
                              void* d_out, int out_size, void* d_ws, size_t ws_size,
                              hipStream_t stream)
{
    const float* x    = (const float*)d_in[0];
    const float* n1w  = (const float*)d_in[1];
    const float* n2w  = (const float*)d_in[2];
    const float* wq   = (const float*)d_in[3];
    const float* wk   = (const float*)d_in[4];
    const float* wv   = (const float*)d_in[5];
    const float* wo   = (const float*)d_in[6];
    const float* bo   = (const float*)d_in[7];
    const float* up   = (const float*)d_in[8];
    const float* vp   = (const float*)d_in[9];
    const float* wpos = (const float*)d_in[10];
    const float* w1   = (const float*)d_in[11];
    const float* b1   = (const float*)d_in[12];
    const float* w2   = (const float*)d_in[13];
    const float* b2   = (const float*)d_in[14];

    char* ws = (char*)d_ws;
    short* h1   = (short*)(ws + 0);         // [4096,768] bf16
    short* qkv  = (short*)(ws + 6291456);   // [4096,1792] bf16, ends 20971520
    float* Tg   = (float*)(ws + 20971520);  // [4096,8,35] f32, ends 25559040
    float* VUg  = (float*)(ws + 25559040);
    float* VSg  = (float*)(ws + 25560064);
    unsigned char* sidx = (unsigned char*)(ws + 25561088);  // [4096]
    short* ao   = (short*)(ws + 25569280);  // [4096,768] bf16
    float* x2   = (float*)(ws + 31860736);  // [4096,768] f32, ends 44443648
    short* vT   = (short*)(ws + 31860736);  // [16,96,2048] bf16 overlays x2 (dead before wo-gemm)
    short* wqkvT= (short*)(ws + 44443648);  // [1792,768] bf16, ends 47196160
    short* woT  = (short*)(ws + 47196160);  // [768,768]
    short* w1T  = (short*)(ws + 48375808);  // [1536,768]
    short* w2T  = (short*)(ws + 50735104);  // [768,1536], ends 53094400
    short* f1   = (short*)(ws + 0);         // [4096,1536] overlays h1+qkv head (dead)
    short* h2n  = (short*)(ws + 14680064);  // [4096,768] overlays qkv tail (dead)

    prep_kernel<<<5153, 256, 0, stream>>>(wq, wk, wv, wo, w1, w2, vp, up, wpos,
                                          wqkvT, woT, w1T, w2T, sidx, VUg, VSg,
                                          x, n1w, h1);
    gemm128<<<dim3(14, 32), 256, 0, stream>>>(h1, wqkvT, nullptr, up, qkv, 4096, 1792, 768, 0);
    qv_kernel<<<512, 256, 0, stream>>>(qkv, wpos, VUg, VSg, Tg, vT);
    flash_kernel<<<dim3(32, 16), 256, 0, stream>>>(qkv, vT, Tg, sidx, ao);
    gemm64<<<dim3(12, 64), 256, 0, stream>>>(ao, woT, bo, x, x2, 4096, 768, 768, 0, 1);
    rmsnorm_kernel<<<4096, 256, 0, stream>>>(x2, n2w, h2n);
    gemm128<<<dim3(12, 32), 256, 0, stream>>>(h2n, w1T, b1, nullptr, f1, 4096, 1536, 768, 1);
    gemm64<<<dim3(12, 64), 256, 0, stream>>>(f1, w2T, b2, x2, d_out, 4096, 768, 1536, 0, 1);
}